// Round 4
// baseline (4583.369 us; speedup 1.0000x reference)
//
#include <hip/hip_runtime.h>

// ---------------------------------------------------------------------------
// arGDPmax_net: 80-step coupled GRU (SDC 128 / world 3968 rows, H=512)
// + segment-max coupling + per-step MLP head.
//
// Round-4 changes vs round-3 (3906us; round-2 was 3128us):
//  - R3's fused k_step regressed because the sdc chain (reg-staged GRU +
//    64-barrier + 64-block G) exceeded the world GEMM and set the kernel
//    duration. New sdc path: 32 blocks (first in dispatch), direct
//    global->VGPR A-fragments (segb unflip in regs; ring bf16 16B loads),
//    only 6KB B-tiles staged via global_load_lds; then a 32-block barrier,
//    segb clear, and G(t+1) by the same blocks. Est. 5-8us, hidden under
//    the ~20us world GEMM (proven R2 code, blocks 32..527). 1 launch/step.
// ---------------------------------------------------------------------------

typedef __attribute__((ext_vector_type(8))) short short8;
typedef __attribute__((ext_vector_type(4))) float f32x4;
typedef unsigned short u16;
typedef unsigned int u32;

#define DEV __device__ __forceinline__

constexpr int S  = 128;
constexpr int NR = 4096;
constexpr int H  = 512;
constexpr int TH = 1536;
constexpr int SLOT = NR * H;
constexpr int SEGSZ = S * H;       // u32 elems per segmax buffer
constexpr int GSZ = S * TH;        // f32 elems per G buffer

struct P {
  const float *goals, *dyn, *ccls, *inte;
  const int *seg;
  const float *sdc_h0, *wld_h0;
  const float *golW, *golb;
  const float *sdcbi, *sdcbh, *wldbi, *wldbh;
  const float *sdco1b, *sdco2W, *sdco2b;
  const float *wldo1b, *wldo2W, *wldo2b;
  const float *sdcWi, *sdcWh, *wldWi, *wldWh, *sdco1W, *wldo1W;
  float *out;
  float *whf;      // [2][4096][512] f32 carried state
  u16   *ring;     // [8][4096][512] bf16 state history
  u16   *enc;      // [4096][512] bf16 encoder output (dead after t=0)
  u16   *WT;       // 4 x [1536][512] bf16: sdcWiT, sdcWhT, wldWiT, wldWhT
  u16   *o1T;      // 2 x [512][512] bf16
  float *G;        // [2][128][1536] f32 (double-buffered)
  u32   *segb;     // [2][128][512] flipped-uint segmax buffers
  u32   *spinc;    // [80] per-step arrival counters
  float *part;     // [4][32768][2] f32 MLP partials (aliases enc)
  int t;
};

DEV u16 f2bf(float f) {
  u32 u = __float_as_uint(f);
  u32 r = u + 0x7FFFu + ((u >> 16) & 1u);
  return (u16)(r >> 16);
}
DEV u32 flipf(float f) {
  u32 u = __float_as_uint(f);
  return (u & 0x80000000u) ? ~u : (u | 0x80000000u);
}
DEV float unflip(u32 s) {
  u32 u = (s & 0x80000000u) ? (s & 0x7FFFFFFFu) : ~s;
  return __uint_as_float(u);
}
DEV float sigm(float x)  { return 1.0f / (1.0f + __expf(-x)); }
DEV float tanh_(float x) { return 2.0f / (1.0f + __expf(-2.0f * x)) - 1.0f; }

DEV f32x4 mfma16(short8 a, short8 b, f32x4 c) {
  return __builtin_amdgcn_mfma_f32_16x16x32_bf16(a, b, c, 0, 0, 0);
}

// async global->LDS, 16B per lane. LDS dest = wave-uniform base + lane*16.
DEV void gload16(const void* g, void* l) {
  __builtin_amdgcn_global_load_lds(
      (const __attribute__((address_space(1))) void*)g,
      (__attribute__((address_space(3))) void*)l, 16, 0, 0);
}

// fragment read honoring the XOR swizzle; row stride 64 elems (128B).
DEV short8 lds_frag(const u16* lds, int row, int g) {
  return *(const short8*)(lds + row * 64 + ((g ^ (row & 7)) << 3));
}

// intra-kernel agent-scope barrier over `target` arriving blocks.
DEV void arrive_wait(u32* cnt, int tid, u32 target) {
  __syncthreads();
  if (tid == 0) {
    __threadfence();
    __hip_atomic_fetch_add(cnt, 1u, __ATOMIC_ACQ_REL, __HIP_MEMORY_SCOPE_AGENT);
    while (__hip_atomic_load(cnt, __ATOMIC_ACQUIRE, __HIP_MEMORY_SCOPE_AGENT) < target)
      __builtin_amdgcn_s_sleep(8);
  }
  __syncthreads();
  __threadfence();
}

// ---------------------------------------------------------------------------
// k_prep: weight transposes, encoder, h0 copy, segb[0..1] clear, spinc clear.
// Grid 1032.
// ---------------------------------------------------------------------------
__global__ __launch_bounds__(256) void k_prep(P p) {
  const int b = blockIdx.x, tid = threadIdx.x;
  __shared__ u16 lt[64 * 72];
  if (b < 896) {
    int nt, kt, Nn; const float* src; u16* dst;
    if (b < 768) {
      int m = b / 192, t2 = b % 192;
      nt = t2 % 24; kt = t2 / 24; Nn = TH;
      src = (m == 0) ? p.sdcWi : (m == 1) ? p.sdcWh : (m == 2) ? p.wldWi : p.wldWh;
      dst = p.WT + m * TH * H;
    } else {
      int bb = b - 768, m = bb / 64, t2 = bb % 64;
      nt = t2 % 8; kt = t2 / 8; Nn = H;
      src = m ? p.wldo1W : p.sdco1W;
      dst = p.o1T + m * H * H;
    }
    for (int it = 0; it < 16; ++it) {
      int kl = it * 4 + (tid >> 6), nl = tid & 63;
      lt[nl * 72 + kl] = f2bf(src[(kt * 64 + kl) * Nn + nt * 64 + nl]);
    }
    __syncthreads();
    for (int it = 0; it < 2; ++it) {
      int nl = it * 32 + (tid >> 3), k8 = (tid & 7) * 8;
      *(short8*)(dst + (nt * 64 + nl) * H + kt * 64 + k8) =
          *(const short8*)(lt + nl * 72 + k8);
    }
  } else if (b < 960) {
    int r0 = (b - 896) * 64;
    for (int i = 0; i < 128; ++i) {
      int idx = i * 256 + tid, row = r0 + (idx >> 9), c = idx & 511;
      float v;
      if (c < 128)      v = p.goals[row*2]*p.golW[c] + p.goals[row*2+1]*p.golW[128+c] + p.golb[c];
      else if (c < 256) v = p.dyn [row*128 + c - 128];
      else if (c < 384) v = p.ccls[row*128 + c - 256];
      else              v = p.inte[row*128 + c - 384];
      p.enc[row * H + c] = f2bf(v);
    }
  } else if (b < 1024) {
    int r0 = (b - 960) * 64;
    for (int i = 0; i < 128; ++i) {
      int idx = i * 256 + tid, row = r0 + (idx >> 9), c = idx & 511;
      float v = (row < S) ? p.sdc_h0[row * H + c] : p.wld_h0[(row - S) * H + c];
      p.whf[SLOT + row * H + c] = v;
      p.ring[7 * SLOT + row * H + c] = f2bf(v);
    }
  } else {                                  // clear both segb buffers + spinc
    int base = (b - 1024) * 16384;
    for (int i = 0; i < 64; ++i) p.segb[base + i * 256 + tid] = 0u;
    if (b == 1024 && tid < 80) p.spinc[tid] = 0u;
  }
}

// ---------------------------------------------------------------------------
// k_big0: step 0 (full gi from enc + gh from h0, all 4096 rows).
// Grid 512 (64 rt x 8 cg), gload16 staging.
// ---------------------------------------------------------------------------
__global__ __launch_bounds__(256) void k_big0(P p) {
  const int b = blockIdx.x, tid = threadIdx.x;
  const int rt = b >> 3, cg = b & 7;
  const bool sdc = rt < 2;
  const int w = tid >> 6, lr = (tid >> 4) & 3, lc = tid & 15;
  __shared__ u16 sm[16384];
  const u16* WiT = p.WT + (sdc ? 0 : 2) * TH * H;
  const u16* WhT = p.WT + (sdc ? 1 : 3) * TH * H;

  f32x4 ai[3][4], ah[3][4];
  f32x4 zero = {0.f, 0.f, 0.f, 0.f};
#pragma unroll
  for (int g = 0; g < 3; ++g)
#pragma unroll
    for (int mt = 0; mt < 4; ++mt) { ai[g][mt] = zero; ah[g][mt] = zero; }

  for (int pass = 0; pass < 2; ++pass) {
    const u16* A  = pass ? (p.ring + 7 * SLOT + rt * 64 * H) : (p.enc + rt * 64 * H);
    const u16* BT = pass ? WhT : WiT;
    for (int kc = 0; kc < H; kc += 64) {
      __syncthreads();
#pragma unroll
      for (int it = 0; it < 8; ++it) {
        int u = it * 256 + tid;
        int gs = (u ^ (u >> 3)) & 7;
        const u16* src;
        if (u < 512) {
          src = A + (u >> 3) * H + kc + gs * 8;
        } else {
          int v = u - 512;
          int g = v >> 9, m = (v >> 3) & 63;
          src = BT + (g * H + cg * 64 + m) * H + kc + gs * 8;
        }
        gload16(src, sm + (it * 256 + (tid & 192)) * 8);
      }
      __syncthreads();
#pragma unroll
      for (int s2 = 0; s2 < 2; ++s2) {
        const int gk = s2 * 4 + lr;
        short8 av[4], bv[3];
#pragma unroll
        for (int mt = 0; mt < 4; ++mt) av[mt] = lds_frag(sm, mt * 16 + lc, gk);
#pragma unroll
        for (int g = 0; g < 3; ++g) bv[g] = lds_frag(sm + 4096 + g * 4096, w * 16 + lc, gk);
#pragma unroll
        for (int g = 0; g < 3; ++g)
#pragma unroll
          for (int mt = 0; mt < 4; ++mt) {
            f32x4 r = pass ? ah[g][mt] : ai[g][mt];
            r = mfma16(av[mt], bv[g], r);
            if (pass) ah[g][mt] = r; else ai[g][mt] = r;
          }
      }
    }
  }
  const float* bi = sdc ? p.sdcbi : p.wldbi;
  const float* bh = sdc ? p.sdcbh : p.wldbh;
  const int col = cg * 64 + w * 16 + lc;
  const float bir = bi[col], biz = bi[H + col], bin = bi[2 * H + col];
  const float bhr = bh[col], bhz = bh[H + col], bhn = bh[2 * H + col];
#pragma unroll
  for (int mt = 0; mt < 4; ++mt)
#pragma unroll
    for (int i = 0; i < 4; ++i) {
      int grow = rt * 64 + mt * 16 + lr * 4 + i;
      float r = sigm(ai[0][mt][i] + bir + ah[0][mt][i] + bhr);
      float z = sigm(ai[1][mt][i] + biz + ah[1][mt][i] + bhz);
      float n = tanh_(ai[2][mt][i] + bin + r * (ah[2][mt][i] + bhn));
      float h = p.whf[SLOT + grow * H + col];
      float h2 = (1.f - z) * n + z * h;
      p.whf[grow * H + col] = h2;
      p.ring[grow * H + col] = f2bf(h2);
      if (!sdc) {
        int scen = p.seg[grow - S];
        atomicMax(p.segb + scen * H + col, flipf(h2));
      }
    }
}

// ---------------------------------------------------------------------------
// G-tile GEMM helper for k_g1 (seeds G(1)).
// ---------------------------------------------------------------------------
DEV void g_tile(const P& p, const u16* A, float* dst, int rh, int cgx,
                int tid, u16* sm) {
  const int w = tid >> 6, lr = (tid >> 4) & 3, lc = tid & 15;
  const u16* Wg = p.WT + 2 * TH * H;     // wld_WiT
  f32x4 acc[3];
  f32x4 zero = {0.f, 0.f, 0.f, 0.f};
#pragma unroll
  for (int g = 0; g < 3; ++g) acc[g] = zero;

  for (int kc = 0; kc < H; kc += 64) {
    __syncthreads();
#pragma unroll
    for (int it = 0; it < 4; ++it) {
      int u = it * 256 + tid;
      if (u < 896) {
        const u16* src;
        if (u < 512) {
          int gs = (u ^ (u >> 3)) & 7;
          src = A + (u >> 3) * H + kc + gs * 8;
        } else {
          int v = u - 512;
          int g = v >> 7, m = (v >> 3) & 15, gs = (v ^ (v >> 3)) & 7;
          src = Wg + (g * H + cgx * 16 + m) * H + kc + gs * 8;
        }
        gload16(src, sm + (it * 256 + (tid & 192)) * 8);
      }
    }
    __syncthreads();
#pragma unroll
    for (int s2 = 0; s2 < 2; ++s2) {
      const int gk = s2 * 4 + lr;
      short8 a = lds_frag(sm, w * 16 + lc, gk);
#pragma unroll
      for (int g = 0; g < 3; ++g)
        acc[g] = mfma16(a, lds_frag(sm + 4096 + g * 1024, lc, gk), acc[g]);
    }
  }
#pragma unroll
  for (int g = 0; g < 3; ++g) {
    int ncol = g * H + cgx * 16 + lc;
    float bi = p.wldbi[ncol];
#pragma unroll
    for (int i = 0; i < 4; ++i)
      dst[(rh * 64 + w * 16 + lr * 4 + i) * TH + ncol] = acc[g][i] + bi;
  }
}

// k_g1: G(1) = sh(0) @ wld_WiT + bi -> G buffer 1. Grid 64 (2 rh x 32 cgx).
__global__ __launch_bounds__(256) void k_g1(P p) {
  const int b = blockIdx.x, tid = threadIdx.x;
  __shared__ u16 sm[8192];
  g_tile(p, p.ring + (b >> 5) * 64 * H, p.G + GSZ, b >> 5, b & 31, tid, sm);
}

// ---------------------------------------------------------------------------
// k_step(t): blocks 0..31:  sdc GRU (direct-global A-frags, 6KB LDS B tiles)
//            -> 32-block barrier -> clear segb[(t-1)&1] -> G(t+1).
//            blocks 32..527: world GRU (gh GEMM + gather(G[t&1]) + gates +
//            run-length-merged segmax atomics -> segb[t&1]).  Grid 528.
// ---------------------------------------------------------------------------
__global__ __launch_bounds__(256) void k_step(P p) {
  const int b = blockIdx.x, tid = threadIdx.x;
  const int w = tid >> 6, lr = (tid >> 4) & 3, lc = tid & 15;
  __shared__ u16 sm[16384];
  const int tp = (p.t - 1) & 7, tn = p.t & 7;
  const float* whfP = p.whf + ((p.t - 1) & 1) * SLOT;
  float* whfN = p.whf + (p.t & 1) * SLOT;
  u16* ringN = p.ring + tn * SLOT;

  if (b >= 32) {  // ---- world GRU ----
    const int rt = (b - 32) >> 3, cg = (b - 32) & 7;
    const u16* Abase = p.ring + tp * SLOT + (S + rt * 64) * H;
    const u16* Bbase = p.WT + 3 * TH * H;      // wld_WhT
    f32x4 acc[3][4];
    f32x4 zero = {0.f, 0.f, 0.f, 0.f};
#pragma unroll
    for (int g = 0; g < 3; ++g)
#pragma unroll
      for (int mt = 0; mt < 4; ++mt) acc[g][mt] = zero;

    for (int kc = 0; kc < H; kc += 64) {
      __syncthreads();
#pragma unroll
      for (int it = 0; it < 8; ++it) {
        int u = it * 256 + tid;
        int gs = (u ^ (u >> 3)) & 7;
        const u16* src;
        if (u < 512) {
          src = Abase + (u >> 3) * H + kc + gs * 8;
        } else {
          int v = u - 512;
          int g = v >> 9, m = (v >> 3) & 63;
          src = Bbase + (g * H + cg * 64 + m) * H + kc + gs * 8;
        }
        gload16(src, sm + (it * 256 + (tid & 192)) * 8);
      }
      __syncthreads();
#pragma unroll
      for (int s2 = 0; s2 < 2; ++s2) {
        const int gk = s2 * 4 + lr;
        short8 av[4], bv[3];
#pragma unroll
        for (int mt = 0; mt < 4; ++mt) av[mt] = lds_frag(sm, mt * 16 + lc, gk);
#pragma unroll
        for (int g = 0; g < 3; ++g) bv[g] = lds_frag(sm + 4096 + g * 4096, w * 16 + lc, gk);
#pragma unroll
        for (int g = 0; g < 3; ++g)
#pragma unroll
          for (int mt = 0; mt < 4; ++mt) acc[g][mt] = mfma16(av[mt], bv[g], acc[g][mt]);
      }
    }
    const int col = cg * 64 + w * 16 + lc;
    const float bhr = p.wldbh[col], bhz = p.wldbh[H + col], bhn = p.wldbh[2 * H + col];
    const float* Gbase = p.G + (p.t & 1) * GSZ;
    u32* sb = p.segb + (p.t & 1) * SEGSZ;
    int curSc = -1; float curMx = 0.f;
#pragma unroll
    for (int mt = 0; mt < 4; ++mt)
#pragma unroll
      for (int i = 0; i < 4; ++i) {
        int wrow = rt * 64 + mt * 16 + lr * 4 + i;
        int grow = S + wrow;
        int scen = p.seg[wrow];
        const float* Gr = Gbase + scen * TH;
        float r = sigm(Gr[col]          + acc[0][mt][i] + bhr);
        float z = sigm(Gr[H + col]      + acc[1][mt][i] + bhz);
        float n = tanh_(Gr[2 * H + col] + r * (acc[2][mt][i] + bhn));
        float h = whfP[grow * H + col];
        float h2 = (1.f - z) * n + z * h;
        whfN[grow * H + col] = h2;
        ringN[grow * H + col] = f2bf(h2);
        if (scen == curSc) curMx = fmaxf(curMx, h2);
        else {
          if (curSc >= 0) atomicMax(sb + curSc * H + col, flipf(curMx));
          curSc = scen; curMx = h2;
        }
      }
    atomicMax(sb + curSc * H + col, flipf(curMx));
  } else {        // ---- sdc GRU (32 blocks x 16 H-cols) + barrier + G ----
    const int hc = b * 16;                 // this block's H-col base
    const u32* segA = p.segb + ((p.t - 1) & 1) * SEGSZ;   // gi A (u32)
    const u16* rA   = p.ring + tp * SLOT;                 // gh A (bf16)

    f32x4 ai[3][2], ah[3][2];
    f32x4 zero = {0.f, 0.f, 0.f, 0.f};
#pragma unroll
    for (int g = 0; g < 3; ++g)
#pragma unroll
      for (int mt = 0; mt < 2; ++mt) { ai[g][mt] = zero; ah[g][mt] = zero; }

    for (int pass = 0; pass < 2; ++pass) {
      const u16* BT = pass ? (p.WT + 1 * TH * H) : p.WT;  // sdcWhT : sdcWiT
      for (int kc = 0; kc < H; kc += 64) {
        __syncthreads();
        {  // stage B 48x64 (384 units = 256 + 128)
          int m = tid >> 3, gs = (tid ^ (tid >> 3)) & 7;
          gload16(BT + ((m >> 4) * H + hc + (m & 15)) * H + kc + gs * 8,
                  sm + (tid & 192) * 8);
        }
        if (tid < 128) {
          int u = 256 + tid;
          int m = u >> 3, gs = (u ^ (u >> 3)) & 7;
          gload16(BT + ((m >> 4) * H + hc + (m & 15)) * H + kc + gs * 8,
                  sm + (256 + (tid & 192)) * 8);
        }
        __syncthreads();
#pragma unroll
        for (int ks = 0; ks < 2; ++ks) {
          const int gk = ks * 4 + lr;
          short8 bv[3];
#pragma unroll
          for (int g = 0; g < 3; ++g) bv[g] = lds_frag(sm, g * 16 + lc, gk);
#pragma unroll
          for (int mt = 0; mt < 2; ++mt) {
            int row = w * 32 + mt * 16 + lc;
            short8 a;
            if (pass) {
              a = *(const short8*)(rA + row * H + kc + ks * 32 + lr * 8);
            } else {
              const u32* pp = segA + row * H + kc + ks * 32 + lr * 8;
#pragma unroll
              for (int e = 0; e < 8; ++e) a[e] = (short)f2bf(unflip(pp[e]));
            }
#pragma unroll
            for (int g = 0; g < 3; ++g) {
              f32x4 r = pass ? ah[g][mt] : ai[g][mt];
              r = mfma16(a, bv[g], r);
              if (pass) ah[g][mt] = r; else ai[g][mt] = r;
            }
          }
        }
      }
    }
    const int col = hc + lc;
    const float bir = p.sdcbi[col], biz = p.sdcbi[H + col], bin = p.sdcbi[2 * H + col];
    const float bhr = p.sdcbh[col], bhz = p.sdcbh[H + col], bhn = p.sdcbh[2 * H + col];
#pragma unroll
    for (int mt = 0; mt < 2; ++mt)
#pragma unroll
      for (int i = 0; i < 4; ++i) {
        int srow = w * 32 + mt * 16 + lr * 4 + i;
        float r = sigm(ai[0][mt][i] + bir + ah[0][mt][i] + bhr);
        float z = sigm(ai[1][mt][i] + biz + ah[1][mt][i] + bhz);
        float n = tanh_(ai[2][mt][i] + bin + r * (ah[2][mt][i] + bhn));
        float h = whfP[srow * H + col];
        float h2 = (1.f - z) * n + z * h;
        whfN[srow * H + col] = h2;
        ringN[srow * H + col] = f2bf(h2);
      }
    // ---- all 32 sdc blocks: sh(t) complete & visible ----
    arrive_wait(p.spinc + p.t, tid, 32u);
    // clear segb[(t-1)&1] for reuse by world atomics at step t+1
    {
      uint4* cb = (uint4*)(p.segb + ((p.t - 1) & 1) * SEGSZ);
      uint4 z4 = make_uint4(0u, 0u, 0u, 0u);
      cb[b * 512 + tid] = z4;
      cb[b * 512 + 256 + tid] = z4;
    }
    // ---- G(t+1) = sh(t) @ wld_WiT + bi -> buffer (t+1)&1 ----
    f32x4 ag[3][2];
#pragma unroll
    for (int g = 0; g < 3; ++g)
#pragma unroll
      for (int mt = 0; mt < 2; ++mt) ag[g][mt] = zero;
    const u16* BTg = p.WT + 2 * TH * H;    // wld_WiT
    for (int kc = 0; kc < H; kc += 64) {
      __syncthreads();
      {
        int m = tid >> 3, gs = (tid ^ (tid >> 3)) & 7;
        gload16(BTg + ((m >> 4) * H + hc + (m & 15)) * H + kc + gs * 8,
                sm + (tid & 192) * 8);
      }
      if (tid < 128) {
        int u = 256 + tid;
        int m = u >> 3, gs = (u ^ (u >> 3)) & 7;
        gload16(BTg + ((m >> 4) * H + hc + (m & 15)) * H + kc + gs * 8,
                sm + (256 + (tid & 192)) * 8);
      }
      __syncthreads();
#pragma unroll
      for (int ks = 0; ks < 2; ++ks) {
        const int gk = ks * 4 + lr;
        short8 bv[3];
#pragma unroll
        for (int g = 0; g < 3; ++g) bv[g] = lds_frag(sm, g * 16 + lc, gk);
#pragma unroll
        for (int mt = 0; mt < 2; ++mt) {
          int row = w * 32 + mt * 16 + lc;
          short8 a = *(const short8*)(ringN + row * H + kc + ks * 32 + lr * 8);
#pragma unroll
          for (int g = 0; g < 3; ++g) ag[g][mt] = mfma16(a, bv[g], ag[g][mt]);
        }
      }
    }
    float* Gd = p.G + ((p.t + 1) & 1) * GSZ;
#pragma unroll
    for (int g = 0; g < 3; ++g) {
      int gcol = g * H + hc + lc;
      float bi = p.wldbi[gcol];
#pragma unroll
      for (int mt = 0; mt < 2; ++mt)
#pragma unroll
        for (int i = 0; i < 4; ++i)
          Gd[(w * 32 + mt * 16 + lr * 4 + i) * TH + gcol] = ag[g][mt][i] + bi;
    }
  }
}

// ---------------------------------------------------------------------------
// k_mlp: per 8-slot batch, layer1 GEMM (128x128 tiles) + fused leaky+layer2
// partials. Grid 1024 = (8 slot x 32 rtile) x 4 ct.
// ---------------------------------------------------------------------------
__global__ __launch_bounds__(256) void k_mlp(P p) {
  const int b = blockIdx.x, tid = threadIdx.x;
  const int rt = b >> 2, ct = b & 3;
  const int slot = rt >> 5, rtile = rt & 31;
  const bool sdc = (rtile == 0);
  const int w = tid >> 6, lr = (tid >> 4) & 3, lc = tid & 15;
  __shared__ u16 sm[16384];
  const u16* A  = p.ring + slot * SLOT + rtile * 128 * H;
  const u16* Bb = p.o1T + (sdc ? 0 : 1) * H * H + (ct * 128) * H;
  const float* o1b = sdc ? p.sdco1b : p.wldo1b;
  const float* o2W = sdc ? p.sdco2W : p.wldo2W;

  f32x4 acc[8][2];
  f32x4 zero = {0.f, 0.f, 0.f, 0.f};
#pragma unroll
  for (int mt = 0; mt < 8; ++mt) { acc[mt][0] = zero; acc[mt][1] = zero; }

  for (int kc = 0; kc < H; kc += 64) {
    __syncthreads();
#pragma unroll
    for (int it = 0; it < 8; ++it) {
      int u = it * 256 + tid;
      int gs = (u ^ (u >> 3)) & 7;
      const u16* src;
      if (u < 1024) src = A  + (u >> 3) * H + kc + gs * 8;
      else          src = Bb + ((u >> 3) & 127) * H + kc + gs * 8;
      gload16(src, sm + (it * 256 + (tid & 192)) * 8);
    }
    __syncthreads();
#pragma unroll
    for (int s2 = 0; s2 < 2; ++s2) {
      const int gk = s2 * 4 + lr;
      short8 av[8], bv[2];
#pragma unroll
      for (int mt = 0; mt < 8; ++mt) av[mt] = lds_frag(sm, mt * 16 + lc, gk);
#pragma unroll
      for (int c2 = 0; c2 < 2; ++c2) bv[c2] = lds_frag(sm + 8192, w * 32 + c2 * 16 + lc, gk);
#pragma unroll
      for (int mt = 0; mt < 8; ++mt)
#pragma unroll
        for (int c2 = 0; c2 < 2; ++c2) acc[mt][c2] = mfma16(av[mt], bv[c2], acc[mt][c2]);
    }
  }
  __syncthreads();
  float* red = (float*)sm;
#pragma unroll
  for (int mt = 0; mt < 8; ++mt) {
    float q0[4] = {0.f, 0.f, 0.f, 0.f}, q1[4] = {0.f, 0.f, 0.f, 0.f};
#pragma unroll
    for (int c2 = 0; c2 < 2; ++c2) {
      int col = ct * 128 + w * 32 + c2 * 16 + lc;
      float b1 = o1b[col], w0 = o2W[col * 2], w1 = o2W[col * 2 + 1];
#pragma unroll
      for (int i = 0; i < 4; ++i) {
        float v = acc[mt][c2][i] + b1;
        v = v > 0.f ? v : 0.1f * v;
        q0[i] += v * w0; q1[i] += v * w1;
      }
    }
#pragma unroll
    for (int off = 1; off < 16; off <<= 1)
#pragma unroll
      for (int i = 0; i < 4; ++i) {
        q0[i] += __shfl_xor(q0[i], off);
        q1[i] += __shfl_xor(q1[i], off);
      }
    if (lc == 0)
#pragma unroll
      for (int i = 0; i < 4; ++i) {
        int row = mt * 16 + lr * 4 + i;
        red[(w * 128 + row) * 2 + 0] = q0[i];
        red[(w * 128 + row) * 2 + 1] = q1[i];
      }
  }
  __syncthreads();
  {
    int row = tid >> 1, od = tid & 1;
    float sum = red[(0 * 128 + row) * 2 + od] + red[(1 * 128 + row) * 2 + od] +
                red[(2 * 128 + row) * 2 + od] + red[(3 * 128 + row) * 2 + od];
    int r = slot * 4096 + rtile * 128 + row;
    p.part[ct * 65536 + r * 2 + od] = sum;
  }
}

// k_mlp2: out = sum of 4 col-quarter partials + o2 bias. Grid 64.
__global__ __launch_bounds__(256) void k_mlp2(P p) {
  const int gtid = blockIdx.x * 256 + threadIdx.x;
  for (int i = gtid; i < 65536; i += 16384) {
    int r = i >> 1, od = i & 1;
    int row = r & 4095, slot = r >> 12;
    float v = p.part[i] + p.part[65536 + i] + p.part[131072 + i] + p.part[196608 + i];
    v += (row < S ? p.sdco2b : p.wldo2b)[od];
    p.out[row * 160 + (p.t + slot) * 2 + od] = v;
  }
}

// ---------------------------------------------------------------------------
extern "C" void kernel_launch(void* const* d_in, const int* in_sizes, int n_in,
                              void* d_out, int out_size, void* d_ws, size_t ws_size,
                              hipStream_t stream) {
  P prm;
  prm.goals  = (const float*)d_in[0];
  prm.dyn    = (const float*)d_in[1];
  prm.ccls   = (const float*)d_in[2];
  prm.inte   = (const float*)d_in[3];
  prm.seg    = (const int*)  d_in[4];
  prm.sdc_h0 = (const float*)d_in[5];
  prm.wld_h0 = (const float*)d_in[6];
  prm.golW   = (const float*)d_in[7];
  prm.golb   = (const float*)d_in[8];
  prm.sdcWi  = (const float*)d_in[9];
  prm.sdcWh  = (const float*)d_in[10];
  prm.sdcbi  = (const float*)d_in[11];
  prm.sdcbh  = (const float*)d_in[12];
  prm.wldWi  = (const float*)d_in[13];
  prm.wldWh  = (const float*)d_in[14];
  prm.wldbi  = (const float*)d_in[15];
  prm.wldbh  = (const float*)d_in[16];
  prm.sdco1W = (const float*)d_in[17];
  prm.sdco1b = (const float*)d_in[18];
  prm.sdco2W = (const float*)d_in[19];
  prm.sdco2b = (const float*)d_in[20];
  prm.wldo1W = (const float*)d_in[21];
  prm.wldo1b = (const float*)d_in[22];
  prm.wldo2W = (const float*)d_in[23];
  prm.wldo2b = (const float*)d_in[24];
  prm.out = (float*)d_out;

  char* ws = (char*)d_ws;
  prm.whf   = (float*)(ws + 0);              // 16,777,216 B
  prm.ring  = (u16*)  (ws + 16777216);       // 33,554,432 B
  prm.enc   = (u16*)  (ws + 50331648);       //  4,194,304 B
  prm.WT    = (u16*)  (ws + 54525952);       //  6,291,456 B
  prm.o1T   = (u16*)  (ws + 60817408);       //  1,048,576 B
  prm.G     = (float*)(ws + 61865984);       //  1,572,864 B (x2 buffers)
  prm.segb  = (u32*)  (ws + 63438848);       //    524,288 B (x2 buffers)
  prm.spinc = (u32*)  (ws + 63963136);       //        320 B
  prm.part  = (float*)(ws + 50331648);       // aliases enc (dead after t=0)

  prm.t = 0;
  k_prep<<<1032, 256, 0, stream>>>(prm);
  k_big0<<<512, 256, 0, stream>>>(prm);
  k_g1<<<64, 256, 0, stream>>>(prm);
  for (int t = 1; t < 80; ++t) {
    prm.t = t;
    k_step<<<528, 256, 0, stream>>>(prm);
    if ((t & 7) == 7) {
      P pm = prm;
      pm.t = t - 7;
      k_mlp<<<1024, 256, 0, stream>>>(pm);
      k_mlp2<<<64, 256, 0, stream>>>(pm);
    }
  }
}

// Round 5
// 4344.008 us; speedup vs baseline: 1.0551x; 1.0551x over previous
//
#include <hip/hip_runtime.h>

// ---------------------------------------------------------------------------
// arGDPmax_net: 80-step coupled GRU (SDC 128 / world 3968 rows, H=512)
// + segment-max coupling + per-step MLP head.
//
// Round-5 (best so far R2=3128us; R3/R4 fusion regressed via barrier-tail):
//  - k_step(t) single launch: blocks 0..47 compute G(t)=sh(t-1)@wld_WiT+bi
//    (prev-kernel data, no wait) + clear segb[t&1], then release gflag[t].
//    World blocks (112..359) poll gflag only at their EPILOGUE (they finish
//    GEMM later than G completes -> no spin). sdc blocks (48..111) are R2's
//    independent LDS-staged GRU, no barrier anywhere on a slow chain.
//  - World GEMM: 128x192 tiles (248 blocks, halves B re-staging) with
//    80KB double-buffered LDS, issue-early gload16 (2-phase pipeline).
//  - k_mlp: same dbuf treatment.
// ---------------------------------------------------------------------------

typedef __attribute__((ext_vector_type(8))) short short8;
typedef __attribute__((ext_vector_type(4))) float f32x4;
typedef unsigned short u16;
typedef unsigned int u32;

#define DEV __device__ __forceinline__

constexpr int S  = 128;
constexpr int NR = 4096;
constexpr int H  = 512;
constexpr int TH = 1536;
constexpr int SLOT = NR * H;
constexpr int SEGSZ = S * H;       // u32 elems per segmax buffer
constexpr int GSZ = S * TH;        // f32 elems in G

struct P {
  const float *goals, *dyn, *ccls, *inte;
  const int *seg;
  const float *sdc_h0, *wld_h0;
  const float *golW, *golb;
  const float *sdcbi, *sdcbh, *wldbi, *wldbh;
  const float *sdco1b, *sdco2W, *sdco2b;
  const float *wldo1b, *wldo2W, *wldo2b;
  const float *sdcWi, *sdcWh, *wldWi, *wldWh, *sdco1W, *wldo1W;
  float *out;
  float *whf;      // [2][4096][512] f32 carried state
  u16   *ring;     // [8][4096][512] bf16 state history
  u16   *enc;      // [4096][512] bf16 encoder output (dead after t=0)
  u16   *WT;       // 4 x [1536][512] bf16: sdcWiT, sdcWhT, wldWiT, wldWhT
  u16   *o1T;      // 2 x [512][512] bf16
  float *G;        // [128][1536] f32 (written+read within one k_step)
  u32   *segb;     // [2][128][512] flipped-uint segmax buffers
  u32   *gflag;    // [80] per-step G-ready counters
  float *part;     // [4][32768][2] f32 MLP partials (aliases enc)
  int t;
};

DEV u16 f2bf(float f) {
  u32 u = __float_as_uint(f);
  u32 r = u + 0x7FFFu + ((u >> 16) & 1u);
  return (u16)(r >> 16);
}
DEV u32 flipf(float f) {
  u32 u = __float_as_uint(f);
  return (u & 0x80000000u) ? ~u : (u | 0x80000000u);
}
DEV float unflip(u32 s) {
  u32 u = (s & 0x80000000u) ? (s & 0x7FFFFFFFu) : ~s;
  return __uint_as_float(u);
}
DEV float sigm(float x)  { return 1.0f / (1.0f + __expf(-x)); }
DEV float tanh_(float x) { return 2.0f / (1.0f + __expf(-2.0f * x)) - 1.0f; }

DEV f32x4 mfma16(short8 a, short8 b, f32x4 c) {
  return __builtin_amdgcn_mfma_f32_16x16x32_bf16(a, b, c, 0, 0, 0);
}

// async global->LDS, 16B per lane. LDS dest = wave-uniform base + lane*16.
DEV void gload16(const void* g, void* l) {
  __builtin_amdgcn_global_load_lds(
      (const __attribute__((address_space(1))) void*)g,
      (__attribute__((address_space(3))) void*)l, 16, 0, 0);
}

// reg-staged tile: LDS unit (m,g) <- src unit (m, g^(m&7)).
DEV void stage_bf(u16* lds, const u16* src, int stride, int rows, int tid) {
  for (int u = tid; u < rows * 8; u += 256) {
    int m = u >> 3, g = u & 7, gs = g ^ (m & 7);
    *(short8*)(lds + (u << 3)) = *(const short8*)(src + m * stride + (gs << 3));
  }
}
// reg-staged from flipped-uint segmax buffer (unflip + cvt). 64 rows.
DEV void stage_seg(u16* lds, const u32* src, int stride, int tid) {
  for (int u = tid; u < 512; u += 256) {
    int m = u >> 3, g = u & 7, gs = g ^ (m & 7);
    const u32* pp = src + m * stride + (gs << 3);
    short8 v;
#pragma unroll
    for (int e = 0; e < 8; ++e) v[e] = (short)f2bf(unflip(pp[e]));
    *(short8*)(lds + (u << 3)) = v;
  }
}
// fragment read honoring the XOR swizzle; row stride 64 elems (128B).
DEV short8 lds_frag(const u16* lds, int row, int g) {
  return *(const short8*)(lds + row * 64 + ((g ^ (row & 7)) << 3));
}

// ---------------------------------------------------------------------------
// k_prep: weight transposes, encoder, h0 copy, segb clear, gflag clear.
// Grid 1032.
// ---------------------------------------------------------------------------
__global__ __launch_bounds__(256) void k_prep(P p) {
  const int b = blockIdx.x, tid = threadIdx.x;
  __shared__ u16 lt[64 * 72];
  if (b < 896) {
    int nt, kt, Nn; const float* src; u16* dst;
    if (b < 768) {
      int m = b / 192, t2 = b % 192;
      nt = t2 % 24; kt = t2 / 24; Nn = TH;
      src = (m == 0) ? p.sdcWi : (m == 1) ? p.sdcWh : (m == 2) ? p.wldWi : p.wldWh;
      dst = p.WT + m * TH * H;
    } else {
      int bb = b - 768, m = bb / 64, t2 = bb % 64;
      nt = t2 % 8; kt = t2 / 8; Nn = H;
      src = m ? p.wldo1W : p.sdco1W;
      dst = p.o1T + m * H * H;
    }
    for (int it = 0; it < 16; ++it) {
      int kl = it * 4 + (tid >> 6), nl = tid & 63;
      lt[nl * 72 + kl] = f2bf(src[(kt * 64 + kl) * Nn + nt * 64 + nl]);
    }
    __syncthreads();
    for (int it = 0; it < 2; ++it) {
      int nl = it * 32 + (tid >> 3), k8 = (tid & 7) * 8;
      *(short8*)(dst + (nt * 64 + nl) * H + kt * 64 + k8) =
          *(const short8*)(lt + nl * 72 + k8);
    }
  } else if (b < 960) {
    int r0 = (b - 896) * 64;
    for (int i = 0; i < 128; ++i) {
      int idx = i * 256 + tid, row = r0 + (idx >> 9), c = idx & 511;
      float v;
      if (c < 128)      v = p.goals[row*2]*p.golW[c] + p.goals[row*2+1]*p.golW[128+c] + p.golb[c];
      else if (c < 256) v = p.dyn [row*128 + c - 128];
      else if (c < 384) v = p.ccls[row*128 + c - 256];
      else              v = p.inte[row*128 + c - 384];
      p.enc[row * H + c] = f2bf(v);
    }
  } else if (b < 1024) {
    int r0 = (b - 960) * 64;
    for (int i = 0; i < 128; ++i) {
      int idx = i * 256 + tid, row = r0 + (idx >> 9), c = idx & 511;
      float v = (row < S) ? p.sdc_h0[row * H + c] : p.wld_h0[(row - S) * H + c];
      p.whf[SLOT + row * H + c] = v;
      p.ring[7 * SLOT + row * H + c] = f2bf(v);
    }
  } else {                                  // clear both segb buffers + gflag
    int base = (b - 1024) * 16384;
    for (int i = 0; i < 64; ++i) p.segb[base + i * 256 + tid] = 0u;
    if (b == 1024 && tid < 80) p.gflag[tid] = 0u;
  }
}

// ---------------------------------------------------------------------------
// k_big0: step 0 (full gi from enc + gh from h0, all 4096 rows).
// Grid 512 (64 rt x 8 cg), gload16 staging (runs once).
// ---------------------------------------------------------------------------
__global__ __launch_bounds__(256) void k_big0(P p) {
  const int b = blockIdx.x, tid = threadIdx.x;
  const int rt = b >> 3, cg = b & 7;
  const bool sdc = rt < 2;
  const int w = tid >> 6, lr = (tid >> 4) & 3, lc = tid & 15;
  __shared__ u16 sm[16384];
  const u16* WiT = p.WT + (sdc ? 0 : 2) * TH * H;
  const u16* WhT = p.WT + (sdc ? 1 : 3) * TH * H;

  f32x4 ai[3][4], ah[3][4];
  f32x4 zero = {0.f, 0.f, 0.f, 0.f};
#pragma unroll
  for (int g = 0; g < 3; ++g)
#pragma unroll
    for (int mt = 0; mt < 4; ++mt) { ai[g][mt] = zero; ah[g][mt] = zero; }

  for (int pass = 0; pass < 2; ++pass) {
    const u16* A  = pass ? (p.ring + 7 * SLOT + rt * 64 * H) : (p.enc + rt * 64 * H);
    const u16* BT = pass ? WhT : WiT;
    for (int kc = 0; kc < H; kc += 64) {
      __syncthreads();
#pragma unroll
      for (int it = 0; it < 8; ++it) {
        int u = it * 256 + tid;
        int gs = (u ^ (u >> 3)) & 7;
        const u16* src;
        if (u < 512) {
          src = A + (u >> 3) * H + kc + gs * 8;
        } else {
          int v = u - 512;
          int g = v >> 9, m = (v >> 3) & 63;
          src = BT + (g * H + cg * 64 + m) * H + kc + gs * 8;
        }
        gload16(src, sm + (it * 256 + (tid & 192)) * 8);
      }
      __syncthreads();
#pragma unroll
      for (int s2 = 0; s2 < 2; ++s2) {
        const int gk = s2 * 4 + lr;
        short8 av[4], bv[3];
#pragma unroll
        for (int mt = 0; mt < 4; ++mt) av[mt] = lds_frag(sm, mt * 16 + lc, gk);
#pragma unroll
        for (int g = 0; g < 3; ++g) bv[g] = lds_frag(sm + 4096 + g * 4096, w * 16 + lc, gk);
#pragma unroll
        for (int g = 0; g < 3; ++g)
#pragma unroll
          for (int mt = 0; mt < 4; ++mt) {
            f32x4 r = pass ? ah[g][mt] : ai[g][mt];
            r = mfma16(av[mt], bv[g], r);
            if (pass) ah[g][mt] = r; else ai[g][mt] = r;
          }
      }
    }
  }
  const float* bi = sdc ? p.sdcbi : p.wldbi;
  const float* bh = sdc ? p.sdcbh : p.wldbh;
  const int col = cg * 64 + w * 16 + lc;
  const float bir = bi[col], biz = bi[H + col], bin = bi[2 * H + col];
  const float bhr = bh[col], bhz = bh[H + col], bhn = bh[2 * H + col];
#pragma unroll
  for (int mt = 0; mt < 4; ++mt)
#pragma unroll
    for (int i = 0; i < 4; ++i) {
      int grow = rt * 64 + mt * 16 + lr * 4 + i;
      float r = sigm(ai[0][mt][i] + bir + ah[0][mt][i] + bhr);
      float z = sigm(ai[1][mt][i] + biz + ah[1][mt][i] + bhz);
      float n = tanh_(ai[2][mt][i] + bin + r * (ah[2][mt][i] + bhn));
      float h = p.whf[SLOT + grow * H + col];
      float h2 = (1.f - z) * n + z * h;
      p.whf[grow * H + col] = h2;
      p.ring[grow * H + col] = f2bf(h2);
      if (!sdc) {
        int scen = p.seg[grow - S];
        atomicMax(p.segb + scen * H + col, flipf(h2));
      }
    }
}

// ---------------------------------------------------------------------------
// k_step(t), grid 360:
//   blocks 0..47   : clear segb[t&1]; G(t)=sh(t-1)@wld_WiT+bi; release gflag[t]
//   blocks 48..111 : sdc GRU (R2 LDS-staged; independent)
//   blocks 112..359: world GRU, 128x192 dbuf tile; poll gflag at epilogue.
// ---------------------------------------------------------------------------
__global__ __launch_bounds__(256) void k_step(P p) {
  const int b = blockIdx.x, tid = threadIdx.x;
  const int w = tid >> 6, lr = (tid >> 4) & 3, lc = tid & 15;
  __shared__ u16 sm[40960];           // 80 KB (world dbuf); other roles use less
  const int tp = (p.t - 1) & 7, tn = p.t & 7;
  const float* whfP = p.whf + ((p.t - 1) & 1) * SLOT;
  float* whfN = p.whf + (p.t & 1) * SLOT;
  u16* ringN = p.ring + tn * SLOT;

  if (b < 48) {  // ---- G-blocks: segb clear + G(t) + flag release ----
    // clear segb[t&1] (world epilogue atomics target; ordered via gflag)
    u32* sb = p.segb + (p.t & 1) * SEGSZ;
    uint4 z4 = make_uint4(0u, 0u, 0u, 0u);
    for (int i = b * 256 + tid; i < 16384; i += 12288) ((uint4*)sb)[i] = z4;
    // G = sh(t-1) @ wld_WiT + bi : 64x64 tile (rh = b/24, nc = b%24)
    const int rh = b / 24, nc = b % 24;
    const u16* Ab = p.ring + tp * SLOT + rh * 64 * H;
    const u16* Wb = p.WT + 2 * TH * H;      // wld_WiT
    f32x4 acc[4];
    f32x4 zero = {0.f, 0.f, 0.f, 0.f};
#pragma unroll
    for (int mt = 0; mt < 4; ++mt) acc[mt] = zero;
    for (int kc = 0; kc < H; kc += 64) {
      __syncthreads();
#pragma unroll
      for (int it = 0; it < 4; ++it) {
        int u = it * 256 + tid;
        int gs = (u ^ (u >> 3)) & 7;
        const u16* src;
        if (u < 512) src = Ab + (u >> 3) * H + kc + gs * 8;
        else         src = Wb + (nc * 64 + ((u >> 3) & 63)) * H + kc + gs * 8;
        gload16(src, sm + (it * 256 + (tid & 192)) * 8);
      }
      __syncthreads();
#pragma unroll
      for (int s2 = 0; s2 < 2; ++s2) {
        const int gk = s2 * 4 + lr;
        short8 bv = lds_frag(sm + 4096, w * 16 + lc, gk);
#pragma unroll
        for (int mt = 0; mt < 4; ++mt)
          acc[mt] = mfma16(lds_frag(sm, mt * 16 + lc, gk), bv, acc[mt]);
      }
    }
    const int colb = nc * 64 + w * 16 + lc;
    const float bi = p.wldbi[colb];
#pragma unroll
    for (int mt = 0; mt < 4; ++mt)
#pragma unroll
      for (int i = 0; i < 4; ++i)
        p.G[(rh * 64 + mt * 16 + lr * 4 + i) * TH + colb] = acc[mt][i] + bi;
    __threadfence();
    __syncthreads();
    if (tid == 0)
      __hip_atomic_fetch_add(p.gflag + p.t, 1u, __ATOMIC_RELEASE,
                             __HIP_MEMORY_SCOPE_AGENT);
  } else if (b < 112) {  // ---- sdc GRU (64 blocks; R2 proven path) ----
    const int ab = b - 48, rh = ab >> 5, cgx = ab & 31;
    const u16* WiT = p.WT;
    const u16* WhT = p.WT + 1 * TH * H;
    u16* ldsA = sm;
    u16* ldsB = sm + 4096;
    f32x4 ai[3], ah[3];
    f32x4 zero = {0.f, 0.f, 0.f, 0.f};
#pragma unroll
    for (int g = 0; g < 3; ++g) { ai[g] = zero; ah[g] = zero; }

    const u32* segP = p.segb + ((p.t - 1) & 1) * SEGSZ;
    for (int pass = 0; pass < 2; ++pass) {
      const u16* Ab = p.ring + tp * SLOT + rh * 64 * H;
      const u16* BT = pass ? WhT : WiT;
      for (int kc = 0; kc < H; kc += 64) {
        __syncthreads();
        if (pass) stage_bf(ldsA, Ab + kc, H, 64, tid);
        else      stage_seg(ldsA, segP + rh * 64 * H + kc, H, tid);
#pragma unroll
        for (int g = 0; g < 3; ++g)
          stage_bf(ldsB + g * 1024, BT + (g * H + cgx * 16) * H + kc, H, 16, tid);
        __syncthreads();
#pragma unroll
        for (int s2 = 0; s2 < 2; ++s2) {
          const int gk = s2 * 4 + lr;
          short8 a = lds_frag(ldsA, w * 16 + lc, gk);
#pragma unroll
          for (int g = 0; g < 3; ++g) {
            f32x4 r = pass ? ah[g] : ai[g];
            r = mfma16(a, lds_frag(ldsB + g * 1024, lc, gk), r);
            if (pass) ah[g] = r; else ai[g] = r;
          }
        }
      }
    }
    const int col = cgx * 16 + lc;
    const float bir = p.sdcbi[col], biz = p.sdcbi[H + col], bin = p.sdcbi[2 * H + col];
    const float bhr = p.sdcbh[col], bhz = p.sdcbh[H + col], bhn = p.sdcbh[2 * H + col];
#pragma unroll
    for (int i = 0; i < 4; ++i) {
      int srow = rh * 64 + w * 16 + lr * 4 + i;
      float r = sigm(ai[0][i] + bir + ah[0][i] + bhr);
      float z = sigm(ai[1][i] + biz + ah[1][i] + bhz);
      float n = tanh_(ai[2][i] + bin + r * (ah[2][i] + bhn));
      float h = whfP[srow * H + col];
      float h2 = (1.f - z) * n + z * h;
      whfN[srow * H + col] = h2;
      ringN[srow * H + col] = f2bf(h2);
    }
  } else {  // ---- world GRU: 128x192 tile, double-buffered staging ----
    const int wb = b - 112;
    const int rt = wb >> 3, cg = wb & 7;        // 31 row-tiles x 8 col-groups
    const u16* Abase = p.ring + tp * SLOT + (S + rt * 128) * H;
    const u16* BbCg  = p.WT + 3 * TH * H + cg * 64 * H;   // wld_WhT col-group
    f32x4 acc[3][8];
    f32x4 zero = {0.f, 0.f, 0.f, 0.f};
#pragma unroll
    for (int g = 0; g < 3; ++g)
#pragma unroll
      for (int mt = 0; mt < 8; ++mt) acc[g][mt] = zero;

    // stage one K-chunk (A 128x64 = 1024 units, B 192x64 = 1536 units) into buf
    auto stage = [&](int kc, u16* buf) {
#pragma unroll
      for (int it = 0; it < 10; ++it) {
        int u = it * 256 + tid;
        const u16* src;
        if (u < 1024) {
          int gs = (u ^ (u >> 3)) & 7;
          src = Abase + (u >> 3) * H + kc + gs * 8;
        } else {
          int v = u - 1024;
          int g = v >> 9, m = (v >> 3) & 63;
          int gs = (v ^ (v >> 3)) & 7;
          src = BbCg + (g * H + m) * H + kc + gs * 8;
        }
        gload16(src, buf + (it * 256 + (tid & 192)) * 8);
      }
    };

    stage(0, sm);
    __syncthreads();
#pragma unroll 1
    for (int kk = 0; kk < 8; ++kk) {
      u16* cur = sm + (kk & 1) * 20480;
      if (kk < 7) stage((kk + 1) * 64, sm + ((kk + 1) & 1) * 20480);  // issue-early
#pragma unroll
      for (int s2 = 0; s2 < 2; ++s2) {
        const int gk = s2 * 4 + lr;
        short8 av[8], bv[3];
#pragma unroll
        for (int mt = 0; mt < 8; ++mt) av[mt] = lds_frag(cur, mt * 16 + lc, gk);
#pragma unroll
        for (int g = 0; g < 3; ++g)
          bv[g] = lds_frag(cur + 8192, g * 64 + w * 16 + lc, gk);
#pragma unroll
        for (int g = 0; g < 3; ++g)
#pragma unroll
          for (int mt = 0; mt < 8; ++mt) acc[g][mt] = mfma16(av[mt], bv[g], acc[g][mt]);
      }
      __syncthreads();   // drains issued staging + frees cur for overwrite
    }

    // ---- wait for G(t) (G-blocks started first; normally already done) ----
    if (tid == 0) {
      while (__hip_atomic_load(p.gflag + p.t, __ATOMIC_ACQUIRE,
                               __HIP_MEMORY_SCOPE_AGENT) < 48u)
        __builtin_amdgcn_s_sleep(2);
    }
    __syncthreads();

    const int col = cg * 64 + w * 16 + lc;
    const float bhr = p.wldbh[col], bhz = p.wldbh[H + col], bhn = p.wldbh[2 * H + col];
    u32* sb = p.segb + (p.t & 1) * SEGSZ;
    int curSc = -1; float curMx = 0.f;
#pragma unroll
    for (int mt = 0; mt < 8; ++mt)
#pragma unroll
      for (int i = 0; i < 4; ++i) {
        int wrow = rt * 128 + mt * 16 + lr * 4 + i;
        int grow = S + wrow;
        int scen = p.seg[wrow];
        const float* Gr = p.G + scen * TH;
        float r = sigm(Gr[col]          + acc[0][mt][i] + bhr);
        float z = sigm(Gr[H + col]      + acc[1][mt][i] + bhz);
        float n = tanh_(Gr[2 * H + col] + r * (acc[2][mt][i] + bhn));
        float h = whfP[grow * H + col];
        float h2 = (1.f - z) * n + z * h;
        whfN[grow * H + col] = h2;
        ringN[grow * H + col] = f2bf(h2);
        if (scen == curSc) curMx = fmaxf(curMx, h2);
        else {
          if (curSc >= 0) atomicMax(sb + curSc * H + col, flipf(curMx));
          curSc = scen; curMx = h2;
        }
      }
    atomicMax(sb + curSc * H + col, flipf(curMx));
  }
}

// ---------------------------------------------------------------------------
// k_mlp: per 8-slot batch, layer1 GEMM (128x128 tiles, dbuf) + fused
// leaky+layer2 partials. Grid 1024 = (8 slot x 32 rtile) x 4 ct.
// ---------------------------------------------------------------------------
__global__ __launch_bounds__(256) void k_mlp(P p) {
  const int b = blockIdx.x, tid = threadIdx.x;
  const int rt = b >> 2, ct = b & 3;
  const int slot = rt >> 5, rtile = rt & 31;
  const bool sdc = (rtile == 0);
  const int w = tid >> 6, lr = (tid >> 4) & 3, lc = tid & 15;
  __shared__ u16 sm[32768];            // 64 KB dbuf
  const u16* A  = p.ring + slot * SLOT + rtile * 128 * H;
  const u16* Bb = p.o1T + (sdc ? 0 : 1) * H * H + (ct * 128) * H;
  const float* o1b = sdc ? p.sdco1b : p.wldo1b;
  const float* o2W = sdc ? p.sdco2W : p.wldo2W;

  f32x4 acc[8][2];
  f32x4 zero = {0.f, 0.f, 0.f, 0.f};
#pragma unroll
  for (int mt = 0; mt < 8; ++mt) { acc[mt][0] = zero; acc[mt][1] = zero; }

  auto stage = [&](int kc, u16* buf) {
#pragma unroll
    for (int it = 0; it < 8; ++it) {
      int u = it * 256 + tid;
      int gs = (u ^ (u >> 3)) & 7;
      const u16* src;
      if (u < 1024) src = A  + (u >> 3) * H + kc + gs * 8;
      else          src = Bb + ((u >> 3) & 127) * H + kc + gs * 8;
      gload16(src, buf + (it * 256 + (tid & 192)) * 8);
    }
  };

  stage(0, sm);
  __syncthreads();
#pragma unroll 1
  for (int kk = 0; kk < 8; ++kk) {
    u16* cur = sm + (kk & 1) * 16384;
    if (kk < 7) stage((kk + 1) * 64, sm + ((kk + 1) & 1) * 16384);
#pragma unroll
    for (int s2 = 0; s2 < 2; ++s2) {
      const int gk = s2 * 4 + lr;
      short8 av[8], bv[2];
#pragma unroll
      for (int mt = 0; mt < 8; ++mt) av[mt] = lds_frag(cur, mt * 16 + lc, gk);
#pragma unroll
      for (int c2 = 0; c2 < 2; ++c2) bv[c2] = lds_frag(cur + 8192, w * 32 + c2 * 16 + lc, gk);
#pragma unroll
      for (int mt = 0; mt < 8; ++mt)
#pragma unroll
        for (int c2 = 0; c2 < 2; ++c2) acc[mt][c2] = mfma16(av[mt], bv[c2], acc[mt][c2]);
    }
    __syncthreads();
  }
  float* red = (float*)sm;
#pragma unroll
  for (int mt = 0; mt < 8; ++mt) {
    float q0[4] = {0.f, 0.f, 0.f, 0.f}, q1[4] = {0.f, 0.f, 0.f, 0.f};
#pragma unroll
    for (int c2 = 0; c2 < 2; ++c2) {
      int col = ct * 128 + w * 32 + c2 * 16 + lc;
      float b1 = o1b[col], w0 = o2W[col * 2], w1 = o2W[col * 2 + 1];
#pragma unroll
      for (int i = 0; i < 4; ++i) {
        float v = acc[mt][c2][i] + b1;
        v = v > 0.f ? v : 0.1f * v;
        q0[i] += v * w0; q1[i] += v * w1;
      }
    }
#pragma unroll
    for (int off = 1; off < 16; off <<= 1)
#pragma unroll
      for (int i = 0; i < 4; ++i) {
        q0[i] += __shfl_xor(q0[i], off);
        q1[i] += __shfl_xor(q1[i], off);
      }
    if (lc == 0)
#pragma unroll
      for (int i = 0; i < 4; ++i) {
        int row = mt * 16 + lr * 4 + i;
        red[(w * 128 + row) * 2 + 0] = q0[i];
        red[(w * 128 + row) * 2 + 1] = q1[i];
      }
  }
  __syncthreads();
  {
    int row = tid >> 1, od = tid & 1;
    float sum = red[(0 * 128 + row) * 2 + od] + red[(1 * 128 + row) * 2 + od] +
                red[(2 * 128 + row) * 2 + od] + red[(3 * 128 + row) * 2 + od];
    int r = slot * 4096 + rtile * 128 + row;
    p.part[ct * 65536 + r * 2 + od] = sum;
  }
}

// k_mlp2: out = sum of 4 col-quarter partials + o2 bias. Grid 64.
__global__ __launch_bounds__(256) void k_mlp2(P p) {
  const int gtid = blockIdx.x * 256 + threadIdx.x;
  for (int i = gtid; i < 65536; i += 16384) {
    int r = i >> 1, od = i & 1;
    int row = r & 4095, slot = r >> 12;
    float v = p.part[i] + p.part[65536 + i] + p.part[131072 + i] + p.part[196608 + i];
    v += (row < S ? p.sdco2b : p.wldo2b)[od];
    p.out[row * 160 + (p.t + slot) * 2 + od] = v;
  }
}

// ---------------------------------------------------------------------------
extern "C" void kernel_launch(void* const* d_in, const int* in_sizes, int n_in,
                              void* d_out, int out_size, void* d_ws, size_t ws_size,
                              hipStream_t stream) {
  P prm;
  prm.goals  = (const float*)d_in[0];
  prm.dyn    = (const float*)d_in[1];
  prm.ccls   = (const float*)d_in[2];
  prm.inte   = (const float*)d_in[3];
  prm.seg    = (const int*)  d_in[4];
  prm.sdc_h0 = (const float*)d_in[5];
  prm.wld_h0 = (const float*)d_in[6];
  prm.golW   = (const float*)d_in[7];
  prm.golb   = (const float*)d_in[8];
  prm.sdcWi  = (const float*)d_in[9];
  prm.sdcWh  = (const float*)d_in[10];
  prm.sdcbi  = (const float*)d_in[11];
  prm.sdcbh  = (const float*)d_in[12];
  prm.wldWi  = (const float*)d_in[13];
  prm.wldWh  = (const float*)d_in[14];
  prm.wldbi  = (const float*)d_in[15];
  prm.wldbh  = (const float*)d_in[16];
  prm.sdco1W = (const float*)d_in[17];
  prm.sdco1b = (const float*)d_in[18];
  prm.sdco2W = (const float*)d_in[19];
  prm.sdco2b = (const float*)d_in[20];
  prm.wldo1W = (const float*)d_in[21];
  prm.wldo1b = (const float*)d_in[22];
  prm.wldo2W = (const float*)d_in[23];
  prm.wldo2b = (const float*)d_in[24];
  prm.out = (float*)d_out;

  char* ws = (char*)d_ws;
  prm.whf   = (float*)(ws + 0);              // 16,777,216 B
  prm.ring  = (u16*)  (ws + 16777216);       // 33,554,432 B
  prm.enc   = (u16*)  (ws + 50331648);       //  4,194,304 B
  prm.WT    = (u16*)  (ws + 54525952);       //  6,291,456 B
  prm.o1T   = (u16*)  (ws + 60817408);       //  1,048,576 B
  prm.G     = (float*)(ws + 61865984);       //    786,432 B
  prm.segb  = (u32*)  (ws + 62652416);       //    524,288 B (x2 buffers)
  prm.gflag = (u32*)  (ws + 63176704);       //        320 B
  prm.part  = (float*)(ws + 50331648);       // aliases enc (dead after t=0)

  prm.t = 0;
  k_prep<<<1032, 256, 0, stream>>>(prm);
  k_big0<<<512, 256, 0, stream>>>(prm);
  for (int t = 1; t < 80; ++t) {
    prm.t = t;
    k_step<<<360, 256, 0, stream>>>(prm);
    if ((t & 7) == 7) {
      P pm = prm;
      pm.t = t - 7;
      k_mlp<<<1024, 256, 0, stream>>>(pm);
      k_mlp2<<<64, 256, 0, stream>>>(pm);
    }
  }
}

// Round 6
// 4214.348 us; speedup vs baseline: 1.0876x; 1.0308x over previous
//
#include <hip/hip_runtime.h>

// ---------------------------------------------------------------------------
// arGDPmax_net: 80-step coupled GRU (SDC 128 / world 3968 rows, H=512)
// + segment-max coupling + per-step MLP head.
//
// Round-6 = R2 (3128us, best proven) + ONLY the G-block fusion from R5:
//  - k_step(t): blocks 0..47 clear segb[t&1] + compute G(t)=sh(t-1)@wld_WiT+bi
//    + release gflag[t]. Blocks 48..111: R2's sdc GRU (LDS-staged, stage_seg).
//    Blocks 112..607: R2's world GRU (64x192 tile, 32KB single-buffer,
//    gload16) polling gflag only at the epilogue. k_small launch eliminated.
//  - k_mlp/k_mlp2: EXACT R2 single-buffer versions (R5's dbuf regressed via
//    occupancy loss; barrier drains vmcnt regardless).
// ---------------------------------------------------------------------------

typedef __attribute__((ext_vector_type(8))) short short8;
typedef __attribute__((ext_vector_type(4))) float f32x4;
typedef unsigned short u16;
typedef unsigned int u32;

#define DEV __device__ __forceinline__

constexpr int S  = 128;
constexpr int NR = 4096;
constexpr int H  = 512;
constexpr int TH = 1536;
constexpr int SLOT = NR * H;
constexpr int SEGSZ = S * H;       // u32 elems per segmax buffer

struct P {
  const float *goals, *dyn, *ccls, *inte;
  const int *seg;
  const float *sdc_h0, *wld_h0;
  const float *golW, *golb;
  const float *sdcbi, *sdcbh, *wldbi, *wldbh;
  const float *sdco1b, *sdco2W, *sdco2b;
  const float *wldo1b, *wldo2W, *wldo2b;
  const float *sdcWi, *sdcWh, *wldWi, *wldWh, *sdco1W, *wldo1W;
  float *out;
  float *whf;      // [2][4096][512] f32 carried state
  u16   *ring;     // [8][4096][512] bf16 state history
  u16   *enc;      // [4096][512] bf16 encoder output (dead after t=0)
  u16   *WT;       // 4 x [1536][512] bf16: sdcWiT, sdcWhT, wldWiT, wldWhT
  u16   *o1T;      // 2 x [512][512] bf16
  float *G;        // [128][1536] f32 (written+read within one k_step)
  u32   *segb;     // [2][128][512] flipped-uint segmax buffers
  u32   *gflag;    // [80] per-step G-ready counters
  float *part;     // [4][32768][2] f32 MLP partials (aliases enc)
  int t;
};

DEV u16 f2bf(float f) {
  u32 u = __float_as_uint(f);
  u32 r = u + 0x7FFFu + ((u >> 16) & 1u);
  return (u16)(r >> 16);
}
DEV u32 flipf(float f) {
  u32 u = __float_as_uint(f);
  return (u & 0x80000000u) ? ~u : (u | 0x80000000u);
}
DEV float unflip(u32 s) {
  u32 u = (s & 0x80000000u) ? (s & 0x7FFFFFFFu) : ~s;
  return __uint_as_float(u);
}
DEV float sigm(float x)  { return 1.0f / (1.0f + __expf(-x)); }
DEV float tanh_(float x) { return 2.0f / (1.0f + __expf(-2.0f * x)) - 1.0f; }

DEV f32x4 mfma16(short8 a, short8 b, f32x4 c) {
  return __builtin_amdgcn_mfma_f32_16x16x32_bf16(a, b, c, 0, 0, 0);
}

// async global->LDS, 16B per lane. LDS dest = wave-uniform base + lane*16.
DEV void gload16(const void* g, void* l) {
  __builtin_amdgcn_global_load_lds(
      (const __attribute__((address_space(1))) void*)g,
      (__attribute__((address_space(3))) void*)l, 16, 0, 0);
}

// reg-staged tile: LDS unit (m,g) <- src unit (m, g^(m&7)).
DEV void stage_bf(u16* lds, const u16* src, int stride, int rows, int tid) {
  for (int u = tid; u < rows * 8; u += 256) {
    int m = u >> 3, g = u & 7, gs = g ^ (m & 7);
    *(short8*)(lds + (u << 3)) = *(const short8*)(src + m * stride + (gs << 3));
  }
}
// reg-staged from flipped-uint segmax buffer (unflip + cvt). 64 rows.
DEV void stage_seg(u16* lds, const u32* src, int stride, int tid) {
  for (int u = tid; u < 512; u += 256) {
    int m = u >> 3, g = u & 7, gs = g ^ (m & 7);
    const u32* pp = src + m * stride + (gs << 3);
    short8 v;
#pragma unroll
    for (int e = 0; e < 8; ++e) v[e] = (short)f2bf(unflip(pp[e]));
    *(short8*)(lds + (u << 3)) = v;
  }
}
// fragment read honoring the XOR swizzle; row stride 64 elems (128B).
DEV short8 lds_frag(const u16* lds, int row, int g) {
  return *(const short8*)(lds + row * 64 + ((g ^ (row & 7)) << 3));
}

// ---------------------------------------------------------------------------
// k_prep: weight transposes, encoder, h0 copy, segb clear, gflag clear.
// Grid 1032.
// ---------------------------------------------------------------------------
__global__ __launch_bounds__(256) void k_prep(P p) {
  const int b = blockIdx.x, tid = threadIdx.x;
  __shared__ u16 lt[64 * 72];
  if (b < 896) {
    int nt, kt, Nn; const float* src; u16* dst;
    if (b < 768) {
      int m = b / 192, t2 = b % 192;
      nt = t2 % 24; kt = t2 / 24; Nn = TH;
      src = (m == 0) ? p.sdcWi : (m == 1) ? p.sdcWh : (m == 2) ? p.wldWi : p.wldWh;
      dst = p.WT + m * TH * H;
    } else {
      int bb = b - 768, m = bb / 64, t2 = bb % 64;
      nt = t2 % 8; kt = t2 / 8; Nn = H;
      src = m ? p.wldo1W : p.sdco1W;
      dst = p.o1T + m * H * H;
    }
    for (int it = 0; it < 16; ++it) {
      int kl = it * 4 + (tid >> 6), nl = tid & 63;
      lt[nl * 72 + kl] = f2bf(src[(kt * 64 + kl) * Nn + nt * 64 + nl]);
    }
    __syncthreads();
    for (int it = 0; it < 2; ++it) {
      int nl = it * 32 + (tid >> 3), k8 = (tid & 7) * 8;
      *(short8*)(dst + (nt * 64 + nl) * H + kt * 64 + k8) =
          *(const short8*)(lt + nl * 72 + k8);
    }
  } else if (b < 960) {
    int r0 = (b - 896) * 64;
    for (int i = 0; i < 128; ++i) {
      int idx = i * 256 + tid, row = r0 + (idx >> 9), c = idx & 511;
      float v;
      if (c < 128)      v = p.goals[row*2]*p.golW[c] + p.goals[row*2+1]*p.golW[128+c] + p.golb[c];
      else if (c < 256) v = p.dyn [row*128 + c - 128];
      else if (c < 384) v = p.ccls[row*128 + c - 256];
      else              v = p.inte[row*128 + c - 384];
      p.enc[row * H + c] = f2bf(v);
    }
  } else if (b < 1024) {
    int r0 = (b - 960) * 64;
    for (int i = 0; i < 128; ++i) {
      int idx = i * 256 + tid, row = r0 + (idx >> 9), c = idx & 511;
      float v = (row < S) ? p.sdc_h0[row * H + c] : p.wld_h0[(row - S) * H + c];
      p.whf[SLOT + row * H + c] = v;
      p.ring[7 * SLOT + row * H + c] = f2bf(v);
    }
  } else {                                  // clear both segb buffers + gflag
    int base = (b - 1024) * 16384;
    for (int i = 0; i < 64; ++i) p.segb[base + i * 256 + tid] = 0u;
    if (b == 1024 && tid < 80) p.gflag[tid] = 0u;
  }
}

// ---------------------------------------------------------------------------
// k_big0: step 0 (full gi from enc + gh from h0, all 4096 rows).
// Grid 512 (64 rt x 8 cg), gload16 staging (runs once).
// ---------------------------------------------------------------------------
__global__ __launch_bounds__(256) void k_big0(P p) {
  const int b = blockIdx.x, tid = threadIdx.x;
  const int rt = b >> 3, cg = b & 7;
  const bool sdc = rt < 2;
  const int w = tid >> 6, lr = (tid >> 4) & 3, lc = tid & 15;
  __shared__ u16 sm[16384];
  const u16* WiT = p.WT + (sdc ? 0 : 2) * TH * H;
  const u16* WhT = p.WT + (sdc ? 1 : 3) * TH * H;

  f32x4 ai[3][4], ah[3][4];
  f32x4 zero = {0.f, 0.f, 0.f, 0.f};
#pragma unroll
  for (int g = 0; g < 3; ++g)
#pragma unroll
    for (int mt = 0; mt < 4; ++mt) { ai[g][mt] = zero; ah[g][mt] = zero; }

  for (int pass = 0; pass < 2; ++pass) {
    const u16* A  = pass ? (p.ring + 7 * SLOT + rt * 64 * H) : (p.enc + rt * 64 * H);
    const u16* BT = pass ? WhT : WiT;
    for (int kc = 0; kc < H; kc += 64) {
      __syncthreads();
#pragma unroll
      for (int it = 0; it < 8; ++it) {
        int u = it * 256 + tid;
        int gs = (u ^ (u >> 3)) & 7;
        const u16* src;
        if (u < 512) {
          src = A + (u >> 3) * H + kc + gs * 8;
        } else {
          int v = u - 512;
          int g = v >> 9, m = (v >> 3) & 63;
          src = BT + (g * H + cg * 64 + m) * H + kc + gs * 8;
        }
        gload16(src, sm + (it * 256 + (tid & 192)) * 8);
      }
      __syncthreads();
#pragma unroll
      for (int s2 = 0; s2 < 2; ++s2) {
        const int gk = s2 * 4 + lr;
        short8 av[4], bv[3];
#pragma unroll
        for (int mt = 0; mt < 4; ++mt) av[mt] = lds_frag(sm, mt * 16 + lc, gk);
#pragma unroll
        for (int g = 0; g < 3; ++g) bv[g] = lds_frag(sm + 4096 + g * 4096, w * 16 + lc, gk);
#pragma unroll
        for (int g = 0; g < 3; ++g)
#pragma unroll
          for (int mt = 0; mt < 4; ++mt) {
            f32x4 r = pass ? ah[g][mt] : ai[g][mt];
            r = mfma16(av[mt], bv[g], r);
            if (pass) ah[g][mt] = r; else ai[g][mt] = r;
          }
      }
    }
  }
  const float* bi = sdc ? p.sdcbi : p.wldbi;
  const float* bh = sdc ? p.sdcbh : p.wldbh;
  const int col = cg * 64 + w * 16 + lc;
  const float bir = bi[col], biz = bi[H + col], bin = bi[2 * H + col];
  const float bhr = bh[col], bhz = bh[H + col], bhn = bh[2 * H + col];
#pragma unroll
  for (int mt = 0; mt < 4; ++mt)
#pragma unroll
    for (int i = 0; i < 4; ++i) {
      int grow = rt * 64 + mt * 16 + lr * 4 + i;
      float r = sigm(ai[0][mt][i] + bir + ah[0][mt][i] + bhr);
      float z = sigm(ai[1][mt][i] + biz + ah[1][mt][i] + bhz);
      float n = tanh_(ai[2][mt][i] + bin + r * (ah[2][mt][i] + bhn));
      float h = p.whf[SLOT + grow * H + col];
      float h2 = (1.f - z) * n + z * h;
      p.whf[grow * H + col] = h2;
      p.ring[grow * H + col] = f2bf(h2);
      if (!sdc) {
        int scen = p.seg[grow - S];
        atomicMax(p.segb + scen * H + col, flipf(h2));
      }
    }
}

// ---------------------------------------------------------------------------
// k_step(t), grid 608:
//   blocks 0..47   : clear segb[t&1]; G(t)=sh(t-1)@wld_WiT+bi; release gflag[t]
//   blocks 48..111 : sdc GRU (R2 LDS-staged path; independent)
//   blocks 112..607: world GRU (R2 64x192 tile, 32KB); poll gflag at epilogue.
// ---------------------------------------------------------------------------
__global__ __launch_bounds__(256) void k_step(P p) {
  const int b = blockIdx.x, tid = threadIdx.x;
  const int w = tid >> 6, lr = (tid >> 4) & 3, lc = tid & 15;
  __shared__ u16 sm[16384];           // 32 KB
  const int tp = (p.t - 1) & 7, tn = p.t & 7;
  const float* whfP = p.whf + ((p.t - 1) & 1) * SLOT;
  float* whfN = p.whf + (p.t & 1) * SLOT;
  u16* ringN = p.ring + tn * SLOT;

  if (b < 48) {  // ---- G-blocks: segb clear + G(t) + flag release ----
    u32* sb = p.segb + (p.t & 1) * SEGSZ;
    uint4 z4 = make_uint4(0u, 0u, 0u, 0u);
    for (int i = b * 256 + tid; i < 16384; i += 12288) ((uint4*)sb)[i] = z4;
    // G = sh(t-1) @ wld_WiT + bi : 64x64 tile (rh = b/24, nc = b%24)
    const int rh = b / 24, nc = b % 24;
    const u16* Ab = p.ring + tp * SLOT + rh * 64 * H;
    const u16* Wb = p.WT + 2 * TH * H;      // wld_WiT
    f32x4 acc[4];
    f32x4 zero = {0.f, 0.f, 0.f, 0.f};
#pragma unroll
    for (int mt = 0; mt < 4; ++mt) acc[mt] = zero;
    for (int kc = 0; kc < H; kc += 64) {
      __syncthreads();
#pragma unroll
      for (int it = 0; it < 4; ++it) {
        int u = it * 256 + tid;
        int gs = (u ^ (u >> 3)) & 7;
        const u16* src;
        if (u < 512) src = Ab + (u >> 3) * H + kc + gs * 8;
        else         src = Wb + (nc * 64 + ((u >> 3) & 63)) * H + kc + gs * 8;
        gload16(src, sm + (it * 256 + (tid & 192)) * 8);
      }
      __syncthreads();
#pragma unroll
      for (int s2 = 0; s2 < 2; ++s2) {
        const int gk = s2 * 4 + lr;
        short8 bv = lds_frag(sm + 4096, w * 16 + lc, gk);
#pragma unroll
        for (int mt = 0; mt < 4; ++mt)
          acc[mt] = mfma16(lds_frag(sm, mt * 16 + lc, gk), bv, acc[mt]);
      }
    }
    const int colb = nc * 64 + w * 16 + lc;
    const float bi = p.wldbi[colb];
#pragma unroll
    for (int mt = 0; mt < 4; ++mt)
#pragma unroll
      for (int i = 0; i < 4; ++i)
        p.G[(rh * 64 + mt * 16 + lr * 4 + i) * TH + colb] = acc[mt][i] + bi;
    __threadfence();
    __syncthreads();
    if (tid == 0)
      __hip_atomic_fetch_add(p.gflag + p.t, 1u, __ATOMIC_RELEASE,
                             __HIP_MEMORY_SCOPE_AGENT);
  } else if (b < 112) {  // ---- sdc GRU (64 blocks; R2 proven path) ----
    const int ab = b - 48, rh = ab >> 5, cgx = ab & 31;
    const u16* WiT = p.WT;
    const u16* WhT = p.WT + 1 * TH * H;
    u16* ldsA = sm;
    u16* ldsB = sm + 4096;
    f32x4 ai[3], ah[3];
    f32x4 zero = {0.f, 0.f, 0.f, 0.f};
#pragma unroll
    for (int g = 0; g < 3; ++g) { ai[g] = zero; ah[g] = zero; }

    const u32* segP = p.segb + ((p.t - 1) & 1) * SEGSZ;
    for (int pass = 0; pass < 2; ++pass) {
      const u16* Ab = p.ring + tp * SLOT + rh * 64 * H;
      const u16* BT = pass ? WhT : WiT;
      for (int kc = 0; kc < H; kc += 64) {
        __syncthreads();
        if (pass) stage_bf(ldsA, Ab + kc, H, 64, tid);
        else      stage_seg(ldsA, segP + rh * 64 * H + kc, H, tid);
#pragma unroll
        for (int g = 0; g < 3; ++g)
          stage_bf(ldsB + g * 1024, BT + (g * H + cgx * 16) * H + kc, H, 16, tid);
        __syncthreads();
#pragma unroll
        for (int s2 = 0; s2 < 2; ++s2) {
          const int gk = s2 * 4 + lr;
          short8 a = lds_frag(ldsA, w * 16 + lc, gk);
#pragma unroll
          for (int g = 0; g < 3; ++g) {
            f32x4 r = pass ? ah[g] : ai[g];
            r = mfma16(a, lds_frag(ldsB + g * 1024, lc, gk), r);
            if (pass) ah[g] = r; else ai[g] = r;
          }
        }
      }
    }
    const int col = cgx * 16 + lc;
    const float bir = p.sdcbi[col], biz = p.sdcbi[H + col], bin = p.sdcbi[2 * H + col];
    const float bhr = p.sdcbh[col], bhz = p.sdcbh[H + col], bhn = p.sdcbh[2 * H + col];
#pragma unroll
    for (int i = 0; i < 4; ++i) {
      int srow = rh * 64 + w * 16 + lr * 4 + i;
      float r = sigm(ai[0][i] + bir + ah[0][i] + bhr);
      float z = sigm(ai[1][i] + biz + ah[1][i] + bhz);
      float n = tanh_(ai[2][i] + bin + r * (ah[2][i] + bhn));
      float h = whfP[srow * H + col];
      float h2 = (1.f - z) * n + z * h;
      whfN[srow * H + col] = h2;
      ringN[srow * H + col] = f2bf(h2);
    }
  } else {  // ---- world GRU (R2 64x192 tile, gload16, 32KB single-buffer) ----
    const int wb = b - 112;
    const int rt = wb >> 3, cg = wb & 7;
    const u16* Abase = p.ring + tp * SLOT + (S + rt * 64) * H;
    const u16* Bbase = p.WT + 3 * TH * H;      // wld_WhT
    f32x4 acc[3][4];
    f32x4 zero = {0.f, 0.f, 0.f, 0.f};
#pragma unroll
    for (int g = 0; g < 3; ++g)
#pragma unroll
      for (int mt = 0; mt < 4; ++mt) acc[g][mt] = zero;

    for (int kc = 0; kc < H; kc += 64) {
      __syncthreads();
#pragma unroll
      for (int it = 0; it < 8; ++it) {
        int u = it * 256 + tid;
        int gs = (u ^ (u >> 3)) & 7;
        const u16* src;
        if (u < 512) {
          src = Abase + (u >> 3) * H + kc + gs * 8;
        } else {
          int v = u - 512;
          int g = v >> 9, m = (v >> 3) & 63;
          src = Bbase + (g * H + cg * 64 + m) * H + kc + gs * 8;
        }
        gload16(src, sm + (it * 256 + (tid & 192)) * 8);
      }
      __syncthreads();
#pragma unroll
      for (int s2 = 0; s2 < 2; ++s2) {
        const int gk = s2 * 4 + lr;
        short8 av[4], bv[3];
#pragma unroll
        for (int mt = 0; mt < 4; ++mt) av[mt] = lds_frag(sm, mt * 16 + lc, gk);
#pragma unroll
        for (int g = 0; g < 3; ++g) bv[g] = lds_frag(sm + 4096 + g * 4096, w * 16 + lc, gk);
#pragma unroll
        for (int g = 0; g < 3; ++g)
#pragma unroll
          for (int mt = 0; mt < 4; ++mt) acc[g][mt] = mfma16(av[mt], bv[g], acc[g][mt]);
      }
    }

    // ---- wait for G(t) (G-blocks started first; normally already done) ----
    if (tid == 0) {
      while (__hip_atomic_load(p.gflag + p.t, __ATOMIC_ACQUIRE,
                               __HIP_MEMORY_SCOPE_AGENT) < 48u)
        __builtin_amdgcn_s_sleep(2);
    }
    __syncthreads();

    const int col = cg * 64 + w * 16 + lc;
    const float bhr = p.wldbh[col], bhz = p.wldbh[H + col], bhn = p.wldbh[2 * H + col];
    u32* sb = p.segb + (p.t & 1) * SEGSZ;
    int curSc = -1; float curMx = 0.f;
#pragma unroll
    for (int mt = 0; mt < 4; ++mt)
#pragma unroll
      for (int i = 0; i < 4; ++i) {
        int wrow = rt * 64 + mt * 16 + lr * 4 + i;
        int grow = S + wrow;
        int scen = p.seg[wrow];
        const float* Gr = p.G + scen * TH;
        float r = sigm(Gr[col]          + acc[0][mt][i] + bhr);
        float z = sigm(Gr[H + col]      + acc[1][mt][i] + bhz);
        float n = tanh_(Gr[2 * H + col] + r * (acc[2][mt][i] + bhn));
        float h = whfP[grow * H + col];
        float h2 = (1.f - z) * n + z * h;
        whfN[grow * H + col] = h2;
        ringN[grow * H + col] = f2bf(h2);
        if (scen == curSc) curMx = fmaxf(curMx, h2);
        else {
          if (curSc >= 0) atomicMax(sb + curSc * H + col, flipf(curMx));
          curSc = scen; curMx = h2;
        }
      }
    atomicMax(sb + curSc * H + col, flipf(curMx));
  }
}

// ---------------------------------------------------------------------------
// k_mlp (R2 exact): layer1 GEMM (128x128 tiles) + fused leaky+layer2 partials.
// Grid 1024 = (8 slot x 32 rtile) x 4 ct.
// ---------------------------------------------------------------------------
__global__ __launch_bounds__(256) void k_mlp(P p) {
  const int b = blockIdx.x, tid = threadIdx.x;
  const int rt = b >> 2, ct = b & 3;
  const int slot = rt >> 5, rtile = rt & 31;
  const bool sdc = (rtile == 0);
  const int w = tid >> 6, lr = (tid >> 4) & 3, lc = tid & 15;
  __shared__ u16 sm[16384];
  const u16* A  = p.ring + slot * SLOT + rtile * 128 * H;
  const u16* Bb = p.o1T + (sdc ? 0 : 1) * H * H + (ct * 128) * H;
  const float* o1b = sdc ? p.sdco1b : p.wldo1b;
  const float* o2W = sdc ? p.sdco2W : p.wldo2W;

  f32x4 acc[8][2];
  f32x4 zero = {0.f, 0.f, 0.f, 0.f};
#pragma unroll
  for (int mt = 0; mt < 8; ++mt) { acc[mt][0] = zero; acc[mt][1] = zero; }

  for (int kc = 0; kc < H; kc += 64) {
    __syncthreads();
#pragma unroll
    for (int it = 0; it < 8; ++it) {
      int u = it * 256 + tid;
      int gs = (u ^ (u >> 3)) & 7;
      const u16* src;
      if (u < 1024) src = A  + (u >> 3) * H + kc + gs * 8;
      else          src = Bb + ((u >> 3) & 127) * H + kc + gs * 8;
      gload16(src, sm + (it * 256 + (tid & 192)) * 8);
    }
    __syncthreads();
#pragma unroll
    for (int s2 = 0; s2 < 2; ++s2) {
      const int gk = s2 * 4 + lr;
      short8 av[8], bv[2];
#pragma unroll
      for (int mt = 0; mt < 8; ++mt) av[mt] = lds_frag(sm, mt * 16 + lc, gk);
#pragma unroll
      for (int c2 = 0; c2 < 2; ++c2) bv[c2] = lds_frag(sm + 8192, w * 32 + c2 * 16 + lc, gk);
#pragma unroll
      for (int mt = 0; mt < 8; ++mt)
#pragma unroll
        for (int c2 = 0; c2 < 2; ++c2) acc[mt][c2] = mfma16(av[mt], bv[c2], acc[mt][c2]);
    }
  }
  __syncthreads();
  float* red = (float*)sm;
#pragma unroll
  for (int mt = 0; mt < 8; ++mt) {
    float q0[4] = {0.f, 0.f, 0.f, 0.f}, q1[4] = {0.f, 0.f, 0.f, 0.f};
#pragma unroll
    for (int c2 = 0; c2 < 2; ++c2) {
      int col = ct * 128 + w * 32 + c2 * 16 + lc;
      float b1 = o1b[col], w0 = o2W[col * 2], w1 = o2W[col * 2 + 1];
#pragma unroll
      for (int i = 0; i < 4; ++i) {
        float v = acc[mt][c2][i] + b1;
        v = v > 0.f ? v : 0.1f * v;
        q0[i] += v * w0; q1[i] += v * w1;
      }
    }
#pragma unroll
    for (int off = 1; off < 16; off <<= 1)
#pragma unroll
      for (int i = 0; i < 4; ++i) {
        q0[i] += __shfl_xor(q0[i], off);
        q1[i] += __shfl_xor(q1[i], off);
      }
    if (lc == 0)
#pragma unroll
      for (int i = 0; i < 4; ++i) {
        int row = mt * 16 + lr * 4 + i;
        red[(w * 128 + row) * 2 + 0] = q0[i];
        red[(w * 128 + row) * 2 + 1] = q1[i];
      }
  }
  __syncthreads();
  {
    int row = tid >> 1, od = tid & 1;
    float sum = red[(0 * 128 + row) * 2 + od] + red[(1 * 128 + row) * 2 + od] +
                red[(2 * 128 + row) * 2 + od] + red[(3 * 128 + row) * 2 + od];
    int r = slot * 4096 + rtile * 128 + row;
    p.part[ct * 65536 + r * 2 + od] = sum;
  }
}

// k_mlp2: out = sum of 4 col-quarter partials + o2 bias. Grid 64.
__global__ __launch_bounds__(256) void k_mlp2(P p) {
  const int gtid = blockIdx.x * 256 + threadIdx.x;
  for (int i = gtid; i < 65536; i += 16384) {
    int r = i >> 1, od = i & 1;
    int row = r & 4095, slot = r >> 12;
    float v = p.part[i] + p.part[65536 + i] + p.part[131072 + i] + p.part[196608 + i];
    v += (row < S ? p.sdco2b : p.wldo2b)[od];
    p.out[row * 160 + (p.t + slot) * 2 + od] = v;
  }
}

// ---------------------------------------------------------------------------
extern "C" void kernel_launch(void* const* d_in, const int* in_sizes, int n_in,
                              void* d_out, int out_size, void* d_ws, size_t ws_size,
                              hipStream_t stream) {
  P prm;
  prm.goals  = (const float*)d_in[0];
  prm.dyn    = (const float*)d_in[1];
  prm.ccls   = (const float*)d_in[2];
  prm.inte   = (const float*)d_in[3];
  prm.seg    = (const int*)  d_in[4];
  prm.sdc_h0 = (const float*)d_in[5];
  prm.wld_h0 = (const float*)d_in[6];
  prm.golW   = (const float*)d_in[7];
  prm.golb   = (const float*)d_in[8];
  prm.sdcWi  = (const float*)d_in[9];
  prm.sdcWh  = (const float*)d_in[10];
  prm.sdcbi  = (const float*)d_in[11];
  prm.sdcbh  = (const float*)d_in[12];
  prm.wldWi  = (const float*)d_in[13];
  prm.wldWh  = (const float*)d_in[14];
  prm.wldbi  = (const float*)d_in[15];
  prm.wldbh  = (const float*)d_in[16];
  prm.sdco1W = (const float*)d_in[17];
  prm.sdco1b = (const float*)d_in[18];
  prm.sdco2W = (const float*)d_in[19];
  prm.sdco2b = (const float*)d_in[20];
  prm.wldo1W = (const float*)d_in[21];
  prm.wldo1b = (const float*)d_in[22];
  prm.wldo2W = (const float*)d_in[23];
  prm.wldo2b = (const float*)d_in[24];
  prm.out = (float*)d_out;

  char* ws = (char*)d_ws;
  prm.whf   = (float*)(ws + 0);              // 16,777,216 B
  prm.ring  = (u16*)  (ws + 16777216);       // 33,554,432 B
  prm.enc   = (u16*)  (ws + 50331648);       //  4,194,304 B
  prm.WT    = (u16*)  (ws + 54525952);       //  6,291,456 B
  prm.o1T   = (u16*)  (ws + 60817408);       //  1,048,576 B
  prm.G     = (float*)(ws + 61865984);       //    786,432 B
  prm.segb  = (u32*)  (ws + 62652416);       //    524,288 B (x2 buffers)
  prm.gflag = (u32*)  (ws + 63176704);       //        320 B
  prm.part  = (float*)(ws + 50331648);       // aliases enc (dead after t=0)

  prm.t = 0;
  k_prep<<<1032, 256, 0, stream>>>(prm);
  k_big0<<<512, 256, 0, stream>>>(prm);
  for (int t = 1; t < 80; ++t) {
    prm.t = t;
    k_step<<<608, 256, 0, stream>>>(prm);
    if ((t & 7) == 7) {
      P pm = prm;
      pm.t = t - 7;
      k_mlp<<<1024, 256, 0, stream>>>(pm);
      k_mlp2<<<64, 256, 0, stream>>>(pm);
    }
  }
}

// Round 7
// 2543.992 us; speedup vs baseline: 1.8016x; 1.6566x over previous
//
#include <hip/hip_runtime.h>

// ---------------------------------------------------------------------------
// arGDPmax_net: 80-step coupled GRU (SDC 128 / world 3968 rows, H=512)
// + segment-max coupling + per-step MLP head.
//
// Round-7 = R2's proven 2-launch/step structure (3128us, NO intra-kernel
// cross-block sync -- R3..R6 spin/barrier fusions all regressed, with 20-40ms
// intermittent spin stalls in the profiles), plus TLP fixes:
//  - k_big: 512-thread blocks (8 waves; was 4). Grid 560 x ~2.2 blocks/CU was
//    only ~9 waves/CU (Occupancy 20%); now ~17.5 waves/CU hides the 8-iter
//    staging/barrier latency chain. Same 64x192 tile, same 32KB LDS, same
//    gload16 staging, bit-identical accumulation order.
//  - k_big sdc path: gload16 staging (from segbf bf16) instead of reg-staged
//    stage_bf; waves 4..7 exit early (AMD barrier ignores exited waves).
//  - k_small: 96 blocks (32-col G tiles) instead of 48 for latency hiding.
// ---------------------------------------------------------------------------

typedef __attribute__((ext_vector_type(8))) short short8;
typedef __attribute__((ext_vector_type(4))) float f32x4;
typedef unsigned short u16;
typedef unsigned int u32;

#define DEV __device__ __forceinline__

constexpr int S  = 128;
constexpr int NR = 4096;
constexpr int H  = 512;
constexpr int TH = 1536;
constexpr int SLOT = NR * H;
constexpr int SEGSZ = S * H;       // u32 elems per segmax buffer

struct P {
  const float *goals, *dyn, *ccls, *inte;
  const int *seg;
  const float *sdc_h0, *wld_h0;
  const float *golW, *golb;
  const float *sdcbi, *sdcbh, *wldbi, *wldbh;
  const float *sdco1b, *sdco2W, *sdco2b;
  const float *wldo1b, *wldo2W, *wldo2b;
  const float *sdcWi, *sdcWh, *wldWi, *wldWh, *sdco1W, *wldo1W;
  float *out;
  float *whf;      // [2][4096][512] f32 carried state
  u16   *ring;     // [8][4096][512] bf16 state history
  u16   *enc;      // [4096][512] bf16 encoder output (dead after t=0)
  u16   *WT;       // 4 x [1536][512] bf16: sdcWiT, sdcWhT, wldWiT, wldWhT
  u16   *o1T;      // 2 x [512][512] bf16
  float *G;        // [128][1536] f32: sh@wld_Wi + bi
  u32   *segb;     // [2][128][512] flipped-uint segmax buffers
  u16   *segbf;    // [128][512] bf16 of prev-step segmax (aliases enc)
  float *part;     // [4][32768][2] f32 MLP partials (aliases enc+128KB)
  int t;
};

DEV u16 f2bf(float f) {
  u32 u = __float_as_uint(f);
  u32 r = u + 0x7FFFu + ((u >> 16) & 1u);
  return (u16)(r >> 16);
}
DEV u32 flipf(float f) {
  u32 u = __float_as_uint(f);
  return (u & 0x80000000u) ? ~u : (u | 0x80000000u);
}
DEV float unflip(u32 s) {
  u32 u = (s & 0x80000000u) ? (s & 0x7FFFFFFFu) : ~s;
  return __uint_as_float(u);
}
DEV float sigm(float x)  { return 1.0f / (1.0f + __expf(-x)); }
DEV float tanh_(float x) { return 2.0f / (1.0f + __expf(-2.0f * x)) - 1.0f; }

DEV f32x4 mfma16(short8 a, short8 b, f32x4 c) {
  return __builtin_amdgcn_mfma_f32_16x16x32_bf16(a, b, c, 0, 0, 0);
}

// async global->LDS, 16B per lane. LDS dest = wave-uniform base + lane*16.
DEV void gload16(const void* g, void* l) {
  __builtin_amdgcn_global_load_lds(
      (const __attribute__((address_space(1))) void*)g,
      (__attribute__((address_space(3))) void*)l, 16, 0, 0);
}

// reg-staged tile (k_prep only): LDS unit (m,g) <- src unit (m, g^(m&7)).
DEV void stage_bf(u16* lds, const u16* src, int stride, int rows, int tid) {
  for (int u = tid; u < rows * 8; u += 256) {
    int m = u >> 3, g = u & 7, gs = g ^ (m & 7);
    *(short8*)(lds + (u << 3)) = *(const short8*)(src + m * stride + (gs << 3));
  }
}
// fragment read honoring the XOR swizzle; row stride 64 elems (128B).
DEV short8 lds_frag(const u16* lds, int row, int g) {
  return *(const short8*)(lds + row * 64 + ((g ^ (row & 7)) << 3));
}

// ---------------------------------------------------------------------------
// k_prep: weight transposes, encoder, h0 copy, segb[0] clear. Grid 1028.
// ---------------------------------------------------------------------------
__global__ __launch_bounds__(256) void k_prep(P p) {
  const int b = blockIdx.x, tid = threadIdx.x;
  __shared__ u16 lt[64 * 72];
  if (b < 896) {
    int nt, kt, Nn; const float* src; u16* dst;
    if (b < 768) {
      int m = b / 192, t2 = b % 192;
      nt = t2 % 24; kt = t2 / 24; Nn = TH;
      src = (m == 0) ? p.sdcWi : (m == 1) ? p.sdcWh : (m == 2) ? p.wldWi : p.wldWh;
      dst = p.WT + m * TH * H;
    } else {
      int bb = b - 768, m = bb / 64, t2 = bb % 64;
      nt = t2 % 8; kt = t2 / 8; Nn = H;
      src = m ? p.wldo1W : p.sdco1W;
      dst = p.o1T + m * H * H;
    }
    for (int it = 0; it < 16; ++it) {
      int kl = it * 4 + (tid >> 6), nl = tid & 63;
      lt[nl * 72 + kl] = f2bf(src[(kt * 64 + kl) * Nn + nt * 64 + nl]);
    }
    __syncthreads();
    for (int it = 0; it < 2; ++it) {
      int nl = it * 32 + (tid >> 3), k8 = (tid & 7) * 8;
      *(short8*)(dst + (nt * 64 + nl) * H + kt * 64 + k8) =
          *(const short8*)(lt + nl * 72 + k8);
    }
  } else if (b < 960) {
    int r0 = (b - 896) * 64;
    for (int i = 0; i < 128; ++i) {
      int idx = i * 256 + tid, row = r0 + (idx >> 9), c = idx & 511;
      float v;
      if (c < 128)      v = p.goals[row*2]*p.golW[c] + p.goals[row*2+1]*p.golW[128+c] + p.golb[c];
      else if (c < 256) v = p.dyn [row*128 + c - 128];
      else if (c < 384) v = p.ccls[row*128 + c - 256];
      else              v = p.inte[row*128 + c - 384];
      p.enc[row * H + c] = f2bf(v);
    }
  } else if (b < 1024) {
    int r0 = (b - 960) * 64;
    for (int i = 0; i < 128; ++i) {
      int idx = i * 256 + tid, row = r0 + (idx >> 9), c = idx & 511;
      float v = (row < S) ? p.sdc_h0[row * H + c] : p.wld_h0[(row - S) * H + c];
      p.whf[SLOT + row * H + c] = v;
      p.ring[7 * SLOT + row * H + c] = f2bf(v);
    }
  } else {                                  // clear segb[0]
    int base = (b - 1024) * 16384;
    for (int i = 0; i < 64; ++i) p.segb[base + i * 256 + tid] = 0u;
  }
}

// ---------------------------------------------------------------------------
// k_big0: step 0 (full gi from enc + gh from h0, all 4096 rows).
// Grid 512 (64 rt x 8 cg), 256 thr, gload16 staging (runs once; R2-proven).
// ---------------------------------------------------------------------------
__global__ __launch_bounds__(256) void k_big0(P p) {
  const int b = blockIdx.x, tid = threadIdx.x;
  const int rt = b >> 3, cg = b & 7;
  const bool sdc = rt < 2;
  const int w = tid >> 6, lr = (tid >> 4) & 3, lc = tid & 15;
  __shared__ u16 sm[16384];
  const u16* WiT = p.WT + (sdc ? 0 : 2) * TH * H;
  const u16* WhT = p.WT + (sdc ? 1 : 3) * TH * H;

  f32x4 ai[3][4], ah[3][4];
  f32x4 zero = {0.f, 0.f, 0.f, 0.f};
#pragma unroll
  for (int g = 0; g < 3; ++g)
#pragma unroll
    for (int mt = 0; mt < 4; ++mt) { ai[g][mt] = zero; ah[g][mt] = zero; }

  for (int pass = 0; pass < 2; ++pass) {
    const u16* A  = pass ? (p.ring + 7 * SLOT + rt * 64 * H) : (p.enc + rt * 64 * H);
    const u16* BT = pass ? WhT : WiT;
    for (int kc = 0; kc < H; kc += 64) {
      __syncthreads();
#pragma unroll
      for (int it = 0; it < 8; ++it) {
        int u = it * 256 + tid;
        int gs = (u ^ (u >> 3)) & 7;
        const u16* src;
        if (u < 512) {
          src = A + (u >> 3) * H + kc + gs * 8;
        } else {
          int v = u - 512;
          int g = v >> 9, m = (v >> 3) & 63;
          src = BT + (g * H + cg * 64 + m) * H + kc + gs * 8;
        }
        gload16(src, sm + (it * 256 + (tid & 192)) * 8);
      }
      __syncthreads();
#pragma unroll
      for (int s2 = 0; s2 < 2; ++s2) {
        const int gk = s2 * 4 + lr;
        short8 av[4], bv[3];
#pragma unroll
        for (int mt = 0; mt < 4; ++mt) av[mt] = lds_frag(sm, mt * 16 + lc, gk);
#pragma unroll
        for (int g = 0; g < 3; ++g) bv[g] = lds_frag(sm + 4096 + g * 4096, w * 16 + lc, gk);
#pragma unroll
        for (int g = 0; g < 3; ++g)
#pragma unroll
          for (int mt = 0; mt < 4; ++mt) {
            f32x4 r = pass ? ah[g][mt] : ai[g][mt];
            r = mfma16(av[mt], bv[g], r);
            if (pass) ah[g][mt] = r; else ai[g][mt] = r;
          }
      }
    }
  }
  const float* bi = sdc ? p.sdcbi : p.wldbi;
  const float* bh = sdc ? p.sdcbh : p.wldbh;
  const int col = cg * 64 + w * 16 + lc;
  const float bir = bi[col], biz = bi[H + col], bin = bi[2 * H + col];
  const float bhr = bh[col], bhz = bh[H + col], bhn = bh[2 * H + col];
#pragma unroll
  for (int mt = 0; mt < 4; ++mt)
#pragma unroll
    for (int i = 0; i < 4; ++i) {
      int grow = rt * 64 + mt * 16 + lr * 4 + i;
      float r = sigm(ai[0][mt][i] + bir + ah[0][mt][i] + bhr);
      float z = sigm(ai[1][mt][i] + biz + ah[1][mt][i] + bhz);
      float n = tanh_(ai[2][mt][i] + bin + r * (ah[2][mt][i] + bhn));
      float h = p.whf[SLOT + grow * H + col];
      float h2 = (1.f - z) * n + z * h;
      p.whf[grow * H + col] = h2;
      p.ring[grow * H + col] = f2bf(h2);
      if (!sdc) {
        int scen = p.seg[grow - S];
        atomicMax(p.segb + scen * H + col, flipf(h2));
      }
    }
}

// ---------------------------------------------------------------------------
// k_small(t): clear segb[t&1]; segbf = bf16(unflip(segb[(t-1)&1]));
//             G = sh_{t-1} @ wld_WiT + bi (128x1536; 96 blocks of 64x32).
// ---------------------------------------------------------------------------
__global__ __launch_bounds__(256) void k_small(P p) {
  const int b = blockIdx.x, tid = threadIdx.x;
  const int gtid = b * 256 + tid;
  // (a) clear this step's segmax buffer
  u32* sb = p.segb + (p.t & 1) * SEGSZ;
  if (gtid < 16384) ((uint4*)sb)[gtid] = make_uint4(0u, 0u, 0u, 0u);
  // (b) convert previous step's segmax to bf16 for k_big's sdc staging
  const u32* sp = p.segb + ((p.t - 1) & 1) * SEGSZ;
  if (gtid < 16384) {
    uint4 q = ((const uint4*)sp)[gtid];
    u32 lo = (u32)f2bf(unflip(q.x)) | ((u32)f2bf(unflip(q.y)) << 16);
    u32 hi = (u32)f2bf(unflip(q.z)) | ((u32)f2bf(unflip(q.w)) << 16);
    ((u32*)p.segbf)[gtid * 2]     = lo;
    ((u32*)p.segbf)[gtid * 2 + 1] = hi;
  }
  // (c) G GEMM: 64x32 tiles, gload16 staging. rh = row half, nc = col tile.
  const int rh = b / 48, nc = b % 48;
  const int wv = tid >> 6, r2 = wv >> 1, c2 = wv & 1;
  const int lr = (tid >> 4) & 3, lc = tid & 15;
  __shared__ u16 sm[6144];            // A 512 units + B 256 units
  const u16* Ab = p.ring + ((p.t - 1) & 7) * SLOT + rh * 64 * H;
  const u16* Wb = p.WT + 2 * TH * H;  // wld_WiT

  f32x4 acc[2];
  f32x4 zero = {0.f, 0.f, 0.f, 0.f};
  acc[0] = zero; acc[1] = zero;

  for (int kc = 0; kc < H; kc += 64) {
    __syncthreads();
#pragma unroll
    for (int it = 0; it < 3; ++it) {
      int u = it * 256 + tid;
      int gs = (u ^ (u >> 3)) & 7;
      const u16* src;
      if (u < 512) src = Ab + (u >> 3) * H + kc + gs * 8;
      else         src = Wb + (nc * 32 + ((u >> 3) & 31)) * H + kc + gs * 8;
      gload16(src, sm + (it * 256 + (tid & 192)) * 8);
    }
    __syncthreads();
#pragma unroll
    for (int s2 = 0; s2 < 2; ++s2) {
      const int gk = s2 * 4 + lr;
      short8 bv = lds_frag(sm + 4096, c2 * 16 + lc, gk);
#pragma unroll
      for (int mt = 0; mt < 2; ++mt)
        acc[mt] = mfma16(lds_frag(sm, r2 * 32 + mt * 16 + lc, gk), bv, acc[mt]);
    }
  }
  const int colb = nc * 32 + c2 * 16 + lc;
  const float bi = p.wldbi[colb];
#pragma unroll
  for (int mt = 0; mt < 2; ++mt)
#pragma unroll
    for (int i = 0; i < 4; ++i)
      p.G[(rh * 64 + r2 * 32 + mt * 16 + lr * 4 + i) * TH + colb] = acc[mt][i] + bi;
}

// ---------------------------------------------------------------------------
// k_big(t), 512 threads/block, grid 560:
//   blocks 0..495 : world GRU. 64x192 tile, 8 waves (2M x 4N), gload16.
//   blocks 496..559: sdc GRU. waves 0..3 active (4..7 exit), gload16 from
//   segbf/ring. No cross-block sync anywhere.
// ---------------------------------------------------------------------------
__global__ __launch_bounds__(512) void k_big(P p) {
  const int b = blockIdx.x, tid = threadIdx.x;
  const int lr = (tid >> 4) & 3, lc = tid & 15;
  __shared__ u16 sm[16384];           // 32 KB
  const int tp = (p.t - 1) & 7, tn = p.t & 7;
  const float* whfP = p.whf + ((p.t - 1) & 1) * SLOT;
  float* whfN = p.whf + (p.t & 1) * SLOT;
  u16* ringN = p.ring + tn * SLOT;

  if (b < 496) {  // ---- world GRU: 8 waves = 2 row-halves x 4 col-quarters ----
    const int wv = tid >> 6, wm = wv >> 2, wn = wv & 3;
    const int rt = b >> 3, cg = b & 7;
    const u16* Abase = p.ring + tp * SLOT + (S + rt * 64) * H;
    const u16* Bbase = p.WT + 3 * TH * H;      // wld_WhT
    f32x4 acc[3][2];
    f32x4 zero = {0.f, 0.f, 0.f, 0.f};
#pragma unroll
    for (int g = 0; g < 3; ++g) { acc[g][0] = zero; acc[g][1] = zero; }

    for (int kc = 0; kc < H; kc += 64) {
      __syncthreads();
#pragma unroll
      for (int it = 0; it < 4; ++it) {
        int u = it * 512 + tid;
        int gs = (u ^ (u >> 3)) & 7;
        const u16* src;
        if (u < 512) {
          src = Abase + (u >> 3) * H + kc + gs * 8;
        } else {
          int v = u - 512;
          int g = v >> 9, m = (v >> 3) & 63;
          src = Bbase + (g * H + cg * 64 + m) * H + kc + gs * 8;
        }
        gload16(src, sm + (it * 512 + (tid & 448)) * 8);
      }
      __syncthreads();
#pragma unroll
      for (int s2 = 0; s2 < 2; ++s2) {
        const int gk = s2 * 4 + lr;
        short8 av[2], bv[3];
#pragma unroll
        for (int mt = 0; mt < 2; ++mt)
          av[mt] = lds_frag(sm, wm * 32 + mt * 16 + lc, gk);
#pragma unroll
        for (int g = 0; g < 3; ++g)
          bv[g] = lds_frag(sm + 4096 + g * 4096, wn * 16 + lc, gk);
#pragma unroll
        for (int g = 0; g < 3; ++g)
#pragma unroll
          for (int mt = 0; mt < 2; ++mt) acc[g][mt] = mfma16(av[mt], bv[g], acc[g][mt]);
      }
    }
    const int col = cg * 64 + wn * 16 + lc;
    const float bhr = p.wldbh[col], bhz = p.wldbh[H + col], bhn = p.wldbh[2 * H + col];
    u32* sb = p.segb + (p.t & 1) * SEGSZ;
    int curSc = -1; float curMx = 0.f;
#pragma unroll
    for (int mt = 0; mt < 2; ++mt)
#pragma unroll
      for (int i = 0; i < 4; ++i) {
        int wrow = rt * 64 + wm * 32 + mt * 16 + lr * 4 + i;
        int grow = S + wrow;
        int scen = p.seg[wrow];
        const float* Gr = p.G + scen * TH;
        float r = sigm(Gr[col]          + acc[0][mt][i] + bhr);
        float z = sigm(Gr[H + col]      + acc[1][mt][i] + bhz);
        float n = tanh_(Gr[2 * H + col] + r * (acc[2][mt][i] + bhn));
        float h = whfP[grow * H + col];
        float h2 = (1.f - z) * n + z * h;
        whfN[grow * H + col] = h2;
        ringN[grow * H + col] = f2bf(h2);
        if (scen == curSc) curMx = fmaxf(curMx, h2);
        else {
          if (curSc >= 0) atomicMax(sb + curSc * H + col, flipf(curMx));
          curSc = scen; curMx = h2;
        }
      }
    atomicMax(sb + curSc * H + col, flipf(curMx));
  } else {        // ---- sdc GRU: waves 0..3 only ----
    const int w = tid >> 6;
    if (w >= 4) return;                 // exited waves don't join barriers
    const int ab = b - 496, rh = ab >> 5, cgx = ab & 31;
    f32x4 ai[3], ah[3];
    f32x4 zero = {0.f, 0.f, 0.f, 0.f};
#pragma unroll
    for (int g = 0; g < 3; ++g) { ai[g] = zero; ah[g] = zero; }

    for (int pass = 0; pass < 2; ++pass) {
      const u16* A  = pass ? (p.ring + tp * SLOT + rh * 64 * H)
                           : (p.segbf + rh * 64 * H);
      const u16* BT = p.WT + (pass ? 1 : 0) * TH * H;   // sdcWhT : sdcWiT
      for (int kc = 0; kc < H; kc += 64) {
        __syncthreads();
#pragma unroll
        for (int it = 0; it < 4; ++it) {
          int u = it * 256 + tid;
          if (u < 896) {
            int gs = (u ^ (u >> 3)) & 7;
            const u16* src;
            if (u < 512) {
              src = A + (u >> 3) * H + kc + gs * 8;
            } else {
              int v = u - 512;
              int m = v >> 3;            // 0..47
              src = BT + ((m >> 4) * H + cgx * 16 + (m & 15)) * H + kc + gs * 8;
            }
            gload16(src, sm + (it * 256 + (tid & 192)) * 8);
          }
        }
        __syncthreads();
#pragma unroll
        for (int s2 = 0; s2 < 2; ++s2) {
          const int gk = s2 * 4 + lr;
          short8 a = lds_frag(sm, w * 16 + lc, gk);
#pragma unroll
          for (int g = 0; g < 3; ++g) {
            f32x4 r = pass ? ah[g] : ai[g];
            r = mfma16(a, lds_frag(sm + 4096, g * 16 + lc, gk), r);
            if (pass) ah[g] = r; else ai[g] = r;
          }
        }
      }
    }
    const int col = cgx * 16 + lc;
    const float bir = p.sdcbi[col], biz = p.sdcbi[H + col], bin = p.sdcbi[2 * H + col];
    const float bhr = p.sdcbh[col], bhz = p.sdcbh[H + col], bhn = p.sdcbh[2 * H + col];
#pragma unroll
    for (int i = 0; i < 4; ++i) {
      int srow = rh * 64 + w * 16 + lr * 4 + i;
      float r = sigm(ai[0][i] + bir + ah[0][i] + bhr);
      float z = sigm(ai[1][i] + biz + ah[1][i] + bhz);
      float n = tanh_(ai[2][i] + bin + r * (ah[2][i] + bhn));
      float h = whfP[srow * H + col];
      float h2 = (1.f - z) * n + z * h;
      whfN[srow * H + col] = h2;
      ringN[srow * H + col] = f2bf(h2);
    }
  }
}

// ---------------------------------------------------------------------------
// k_mlp (R2 exact): layer1 GEMM (128x128 tiles) + fused leaky+layer2 partials.
// Grid 1024 = (8 slot x 32 rtile) x 4 ct.
// ---------------------------------------------------------------------------
__global__ __launch_bounds__(256) void k_mlp(P p) {
  const int b = blockIdx.x, tid = threadIdx.x;
  const int rt = b >> 2, ct = b & 3;
  const int slot = rt >> 5, rtile = rt & 31;
  const bool sdc = (rtile == 0);
  const int w = tid >> 6, lr = (tid >> 4) & 3, lc = tid & 15;
  __shared__ u16 sm[16384];
  const u16* A  = p.ring + slot * SLOT + rtile * 128 * H;
  const u16* Bb = p.o1T + (sdc ? 0 : 1) * H * H + (ct * 128) * H;
  const float* o1b = sdc ? p.sdco1b : p.wldo1b;
  const float* o2W = sdc ? p.sdco2W : p.wldo2W;

  f32x4 acc[8][2];
  f32x4 zero = {0.f, 0.f, 0.f, 0.f};
#pragma unroll
  for (int mt = 0; mt < 8; ++mt) { acc[mt][0] = zero; acc[mt][1] = zero; }

  for (int kc = 0; kc < H; kc += 64) {
    __syncthreads();
#pragma unroll
    for (int it = 0; it < 8; ++it) {
      int u = it * 256 + tid;
      int gs = (u ^ (u >> 3)) & 7;
      const u16* src;
      if (u < 1024) src = A  + (u >> 3) * H + kc + gs * 8;
      else          src = Bb + ((u >> 3) & 127) * H + kc + gs * 8;
      gload16(src, sm + (it * 256 + (tid & 192)) * 8);
    }
    __syncthreads();
#pragma unroll
    for (int s2 = 0; s2 < 2; ++s2) {
      const int gk = s2 * 4 + lr;
      short8 av[8], bv[2];
#pragma unroll
      for (int mt = 0; mt < 8; ++mt) av[mt] = lds_frag(sm, mt * 16 + lc, gk);
#pragma unroll
      for (int c2 = 0; c2 < 2; ++c2) bv[c2] = lds_frag(sm + 8192, w * 32 + c2 * 16 + lc, gk);
#pragma unroll
      for (int mt = 0; mt < 8; ++mt)
#pragma unroll
        for (int c2 = 0; c2 < 2; ++c2) acc[mt][c2] = mfma16(av[mt], bv[c2], acc[mt][c2]);
    }
  }
  __syncthreads();
  float* red = (float*)sm;
#pragma unroll
  for (int mt = 0; mt < 8; ++mt) {
    float q0[4] = {0.f, 0.f, 0.f, 0.f}, q1[4] = {0.f, 0.f, 0.f, 0.f};
#pragma unroll
    for (int c2 = 0; c2 < 2; ++c2) {
      int col = ct * 128 + w * 32 + c2 * 16 + lc;
      float b1 = o1b[col], w0 = o2W[col * 2], w1 = o2W[col * 2 + 1];
#pragma unroll
      for (int i = 0; i < 4; ++i) {
        float v = acc[mt][c2][i] + b1;
        v = v > 0.f ? v : 0.1f * v;
        q0[i] += v * w0; q1[i] += v * w1;
      }
    }
#pragma unroll
    for (int off = 1; off < 16; off <<= 1)
#pragma unroll
      for (int i = 0; i < 4; ++i) {
        q0[i] += __shfl_xor(q0[i], off);
        q1[i] += __shfl_xor(q1[i], off);
      }
    if (lc == 0)
#pragma unroll
      for (int i = 0; i < 4; ++i) {
        int row = mt * 16 + lr * 4 + i;
        red[(w * 128 + row) * 2 + 0] = q0[i];
        red[(w * 128 + row) * 2 + 1] = q1[i];
      }
  }
  __syncthreads();
  {
    int row = tid >> 1, od = tid & 1;
    float sum = red[(0 * 128 + row) * 2 + od] + red[(1 * 128 + row) * 2 + od] +
                red[(2 * 128 + row) * 2 + od] + red[(3 * 128 + row) * 2 + od];
    int r = slot * 4096 + rtile * 128 + row;
    p.part[ct * 65536 + r * 2 + od] = sum;
  }
}

// k_mlp2: out = sum of 4 col-quarter partials + o2 bias. Grid 64.
__global__ __launch_bounds__(256) void k_mlp2(P p) {
  const int gtid = blockIdx.x * 256 + threadIdx.x;
  for (int i = gtid; i < 65536; i += 16384) {
    int r = i >> 1, od = i & 1;
    int row = r & 4095, slot = r >> 12;
    float v = p.part[i] + p.part[65536 + i] + p.part[131072 + i] + p.part[196608 + i];
    v += (row < S ? p.sdco2b : p.wldo2b)[od];
    p.out[row * 160 + (p.t + slot) * 2 + od] = v;
  }
}

// ---------------------------------------------------------------------------
extern "C" void kernel_launch(void* const* d_in, const int* in_sizes, int n_in,
                              void* d_out, int out_size, void* d_ws, size_t ws_size,
                              hipStream_t stream) {
  P prm;
  prm.goals  = (const float*)d_in[0];
  prm.dyn    = (const float*)d_in[1];
  prm.ccls   = (const float*)d_in[2];
  prm.inte   = (const float*)d_in[3];
  prm.seg    = (const int*)  d_in[4];
  prm.sdc_h0 = (const float*)d_in[5];
  prm.wld_h0 = (const float*)d_in[6];
  prm.golW   = (const float*)d_in[7];
  prm.golb   = (const float*)d_in[8];
  prm.sdcWi  = (const float*)d_in[9];
  prm.sdcWh  = (const float*)d_in[10];
  prm.sdcbi  = (const float*)d_in[11];
  prm.sdcbh  = (const float*)d_in[12];
  prm.wldWi  = (const float*)d_in[13];
  prm.wldWh  = (const float*)d_in[14];
  prm.wldbi  = (const float*)d_in[15];
  prm.wldbh  = (const float*)d_in[16];
  prm.sdco1W = (const float*)d_in[17];
  prm.sdco1b = (const float*)d_in[18];
  prm.sdco2W = (const float*)d_in[19];
  prm.sdco2b = (const float*)d_in[20];
  prm.wldo1W = (const float*)d_in[21];
  prm.wldo1b = (const float*)d_in[22];
  prm.wldo2W = (const float*)d_in[23];
  prm.wldo2b = (const float*)d_in[24];
  prm.out = (float*)d_out;

  char* ws = (char*)d_ws;
  prm.whf   = (float*)(ws + 0);              // 16,777,216 B
  prm.ring  = (u16*)  (ws + 16777216);       // 33,554,432 B
  prm.enc   = (u16*)  (ws + 50331648);       //  4,194,304 B
  prm.WT    = (u16*)  (ws + 54525952);       //  6,291,456 B
  prm.o1T   = (u16*)  (ws + 60817408);       //  1,048,576 B
  prm.G     = (float*)(ws + 61865984);       //    786,432 B
  prm.segb  = (u32*)  (ws + 62652416);       //    524,288 B (x2 buffers)
  prm.segbf = (u16*)  (ws + 50331648);           // aliases enc (dead after t=0)
  prm.part  = (float*)(ws + 50331648 + 131072);  // aliases enc+128KB (1 MB)

  prm.t = 0;
  k_prep<<<1028, 256, 0, stream>>>(prm);
  k_big0<<<512, 256, 0, stream>>>(prm);
  for (int t = 1; t < 80; ++t) {
    prm.t = t;
    k_small<<<96, 256, 0, stream>>>(prm);
    k_big<<<560, 512, 0, stream>>>(prm);
    if ((t & 7) == 7) {
      P pm = prm;
      pm.t = t - 7;
      k_mlp<<<1024, 256, 0, stream>>>(pm);
      k_mlp2<<<64, 256, 0, stream>>>(pm);
    }
  }
}

// Round 8
// 2442.072 us; speedup vs baseline: 1.8768x; 1.0417x over previous
//
#include <hip/hip_runtime.h>

// ---------------------------------------------------------------------------
// arGDPmax_net: 80-step coupled GRU (SDC 128 / world 3968 rows, H=512)
// + segment-max coupling + per-step MLP head.
//
// Round-8 = R7 (2544us) + two safe shavings:
//  - k_small: 48 blocks x 512 threads, two-K-chunk staging per barrier pair
//    (4 outer iters / 8 barriers, was 8/16 at 96x256). Latency-bound kernel;
//    K-accumulation order preserved -> bit-identical.
//  - k_prep transpose: f32 LDS [64][65] (conflict-free; measured 372K bank
//    conflicts came from the u16 stride-72 tile). bf16 cvt moved to read side.
// R7 core retained: 2 launches/step, NO intra-kernel cross-block sync
// (R3..R6 all regressed via multi-ms spin stalls), k_big 512-thr 64x192.
// ---------------------------------------------------------------------------

typedef __attribute__((ext_vector_type(8))) short short8;
typedef __attribute__((ext_vector_type(4))) float f32x4;
typedef unsigned short u16;
typedef unsigned int u32;

#define DEV __device__ __forceinline__

constexpr int S  = 128;
constexpr int NR = 4096;
constexpr int H  = 512;
constexpr int TH = 1536;
constexpr int SLOT = NR * H;
constexpr int SEGSZ = S * H;       // u32 elems per segmax buffer

struct P {
  const float *goals, *dyn, *ccls, *inte;
  const int *seg;
  const float *sdc_h0, *wld_h0;
  const float *golW, *golb;
  const float *sdcbi, *sdcbh, *wldbi, *wldbh;
  const float *sdco1b, *sdco2W, *sdco2b;
  const float *wldo1b, *wldo2W, *wldo2b;
  const float *sdcWi, *sdcWh, *wldWi, *wldWh, *sdco1W, *wldo1W;
  float *out;
  float *whf;      // [2][4096][512] f32 carried state
  u16   *ring;     // [8][4096][512] bf16 state history
  u16   *enc;      // [4096][512] bf16 encoder output (dead after t=0)
  u16   *WT;       // 4 x [1536][512] bf16: sdcWiT, sdcWhT, wldWiT, wldWhT
  u16   *o1T;      // 2 x [512][512] bf16
  float *G;        // [128][1536] f32: sh@wld_Wi + bi
  u32   *segb;     // [2][128][512] flipped-uint segmax buffers
  u16   *segbf;    // [128][512] bf16 of prev-step segmax (aliases enc)
  float *part;     // [4][32768][2] f32 MLP partials (aliases enc+128KB)
  int t;
};

DEV u16 f2bf(float f) {
  u32 u = __float_as_uint(f);
  u32 r = u + 0x7FFFu + ((u >> 16) & 1u);
  return (u16)(r >> 16);
}
DEV u32 flipf(float f) {
  u32 u = __float_as_uint(f);
  return (u & 0x80000000u) ? ~u : (u | 0x80000000u);
}
DEV float unflip(u32 s) {
  u32 u = (s & 0x80000000u) ? (s & 0x7FFFFFFFu) : ~s;
  return __uint_as_float(u);
}
DEV float sigm(float x)  { return 1.0f / (1.0f + __expf(-x)); }
DEV float tanh_(float x) { return 2.0f / (1.0f + __expf(-2.0f * x)) - 1.0f; }

DEV f32x4 mfma16(short8 a, short8 b, f32x4 c) {
  return __builtin_amdgcn_mfma_f32_16x16x32_bf16(a, b, c, 0, 0, 0);
}

// async global->LDS, 16B per lane. LDS dest = wave-uniform base + lane*16.
DEV void gload16(const void* g, void* l) {
  __builtin_amdgcn_global_load_lds(
      (const __attribute__((address_space(1))) void*)g,
      (__attribute__((address_space(3))) void*)l, 16, 0, 0);
}

// fragment read honoring the XOR swizzle; row stride 64 elems (128B).
DEV short8 lds_frag(const u16* lds, int row, int g) {
  return *(const short8*)(lds + row * 64 + ((g ^ (row & 7)) << 3));
}

// ---------------------------------------------------------------------------
// k_prep: weight transposes (f32 LDS [64][65], conflict-free), encoder,
// h0 copy, segb[0] clear. Grid 1028.
// ---------------------------------------------------------------------------
__global__ __launch_bounds__(256) void k_prep(P p) {
  const int b = blockIdx.x, tid = threadIdx.x;
  __shared__ float ltf[64 * 65];
  if (b < 896) {
    int nt, kt, Nn; const float* src; u16* dst;
    if (b < 768) {
      int m = b / 192, t2 = b % 192;
      nt = t2 % 24; kt = t2 / 24; Nn = TH;
      src = (m == 0) ? p.sdcWi : (m == 1) ? p.sdcWh : (m == 2) ? p.wldWi : p.wldWh;
      dst = p.WT + m * TH * H;
    } else {
      int bb = b - 768, m = bb / 64, t2 = bb % 64;
      nt = t2 % 8; kt = t2 / 8; Nn = H;
      src = m ? p.wldo1W : p.sdco1W;
      dst = p.o1T + m * H * H;
    }
    for (int it = 0; it < 16; ++it) {
      int kl = it * 4 + (tid >> 6), nl = tid & 63;
      ltf[nl * 65 + kl] = src[(kt * 64 + kl) * Nn + nt * 64 + nl];
    }
    __syncthreads();
    for (int it = 0; it < 2; ++it) {
      int nl = it * 32 + (tid >> 3), k8 = (tid & 7) * 8;
      short8 v;
#pragma unroll
      for (int e = 0; e < 8; ++e) v[e] = (short)f2bf(ltf[nl * 65 + k8 + e]);
      *(short8*)(dst + (nt * 64 + nl) * H + kt * 64 + k8) = v;
    }
  } else if (b < 960) {
    int r0 = (b - 896) * 64;
    for (int i = 0; i < 128; ++i) {
      int idx = i * 256 + tid, row = r0 + (idx >> 9), c = idx & 511;
      float v;
      if (c < 128)      v = p.goals[row*2]*p.golW[c] + p.goals[row*2+1]*p.golW[128+c] + p.golb[c];
      else if (c < 256) v = p.dyn [row*128 + c - 128];
      else if (c < 384) v = p.ccls[row*128 + c - 256];
      else              v = p.inte[row*128 + c - 384];
      p.enc[row * H + c] = f2bf(v);
    }
  } else if (b < 1024) {
    int r0 = (b - 960) * 64;
    for (int i = 0; i < 128; ++i) {
      int idx = i * 256 + tid, row = r0 + (idx >> 9), c = idx & 511;
      float v = (row < S) ? p.sdc_h0[row * H + c] : p.wld_h0[(row - S) * H + c];
      p.whf[SLOT + row * H + c] = v;
      p.ring[7 * SLOT + row * H + c] = f2bf(v);
    }
  } else {                                  // clear segb[0]
    int base = (b - 1024) * 16384;
    for (int i = 0; i < 64; ++i) p.segb[base + i * 256 + tid] = 0u;
  }
}

// ---------------------------------------------------------------------------
// k_big0: step 0 (full gi from enc + gh from h0, all 4096 rows).
// Grid 512 (64 rt x 8 cg), 256 thr, gload16 staging (runs once; R2-proven).
// ---------------------------------------------------------------------------
__global__ __launch_bounds__(256) void k_big0(P p) {
  const int b = blockIdx.x, tid = threadIdx.x;
  const int rt = b >> 3, cg = b & 7;
  const bool sdc = rt < 2;
  const int w = tid >> 6, lr = (tid >> 4) & 3, lc = tid & 15;
  __shared__ u16 sm[16384];
  const u16* WiT = p.WT + (sdc ? 0 : 2) * TH * H;
  const u16* WhT = p.WT + (sdc ? 1 : 3) * TH * H;

  f32x4 ai[3][4], ah[3][4];
  f32x4 zero = {0.f, 0.f, 0.f, 0.f};
#pragma unroll
  for (int g = 0; g < 3; ++g)
#pragma unroll
    for (int mt = 0; mt < 4; ++mt) { ai[g][mt] = zero; ah[g][mt] = zero; }

  for (int pass = 0; pass < 2; ++pass) {
    const u16* A  = pass ? (p.ring + 7 * SLOT + rt * 64 * H) : (p.enc + rt * 64 * H);
    const u16* BT = pass ? WhT : WiT;
    for (int kc = 0; kc < H; kc += 64) {
      __syncthreads();
#pragma unroll
      for (int it = 0; it < 8; ++it) {
        int u = it * 256 + tid;
        int gs = (u ^ (u >> 3)) & 7;
        const u16* src;
        if (u < 512) {
          src = A + (u >> 3) * H + kc + gs * 8;
        } else {
          int v = u - 512;
          int g = v >> 9, m = (v >> 3) & 63;
          src = BT + (g * H + cg * 64 + m) * H + kc + gs * 8;
        }
        gload16(src, sm + (it * 256 + (tid & 192)) * 8);
      }
      __syncthreads();
#pragma unroll
      for (int s2 = 0; s2 < 2; ++s2) {
        const int gk = s2 * 4 + lr;
        short8 av[4], bv[3];
#pragma unroll
        for (int mt = 0; mt < 4; ++mt) av[mt] = lds_frag(sm, mt * 16 + lc, gk);
#pragma unroll
        for (int g = 0; g < 3; ++g) bv[g] = lds_frag(sm + 4096 + g * 4096, w * 16 + lc, gk);
#pragma unroll
        for (int g = 0; g < 3; ++g)
#pragma unroll
          for (int mt = 0; mt < 4; ++mt) {
            f32x4 r = pass ? ah[g][mt] : ai[g][mt];
            r = mfma16(av[mt], bv[g], r);
            if (pass) ah[g][mt] = r; else ai[g][mt] = r;
          }
      }
    }
  }
  const float* bi = sdc ? p.sdcbi : p.wldbi;
  const float* bh = sdc ? p.sdcbh : p.wldbh;
  const int col = cg * 64 + w * 16 + lc;
  const float bir = bi[col], biz = bi[H + col], bin = bi[2 * H + col];
  const float bhr = bh[col], bhz = bh[H + col], bhn = bh[2 * H + col];
#pragma unroll
  for (int mt = 0; mt < 4; ++mt)
#pragma unroll
    for (int i = 0; i < 4; ++i) {
      int grow = rt * 64 + mt * 16 + lr * 4 + i;
      float r = sigm(ai[0][mt][i] + bir + ah[0][mt][i] + bhr);
      float z = sigm(ai[1][mt][i] + biz + ah[1][mt][i] + bhz);
      float n = tanh_(ai[2][mt][i] + bin + r * (ah[2][mt][i] + bhn));
      float h = p.whf[SLOT + grow * H + col];
      float h2 = (1.f - z) * n + z * h;
      p.whf[grow * H + col] = h2;
      p.ring[grow * H + col] = f2bf(h2);
      if (!sdc) {
        int scen = p.seg[grow - S];
        atomicMax(p.segb + scen * H + col, flipf(h2));
      }
    }
}

// ---------------------------------------------------------------------------
// k_small(t): clear segb[t&1]; segbf = bf16(unflip(segb[(t-1)&1]));
//             G = sh_{t-1} @ wld_WiT + bi.
// Grid 48 x 512 threads. Tile 64x64 (rh = b/24, nc = b%24).
// Two K-chunks staged per barrier pair: 4 outer iters / 8 barriers.
// ---------------------------------------------------------------------------
__global__ __launch_bounds__(512) void k_small(P p) {
  const int b = blockIdx.x, tid = threadIdx.x;
  const int gtid = b * 512 + tid;
  // (a) clear this step's segmax buffer
  u32* sb = p.segb + (p.t & 1) * SEGSZ;
  if (gtid < 16384) ((uint4*)sb)[gtid] = make_uint4(0u, 0u, 0u, 0u);
  // (b) convert previous step's segmax to bf16 for k_big's sdc staging
  const u32* sp = p.segb + ((p.t - 1) & 1) * SEGSZ;
  if (gtid < 16384) {
    uint4 q = ((const uint4*)sp)[gtid];
    u32 lo = (u32)f2bf(unflip(q.x)) | ((u32)f2bf(unflip(q.y)) << 16);
    u32 hi = (u32)f2bf(unflip(q.z)) | ((u32)f2bf(unflip(q.w)) << 16);
    ((u32*)p.segbf)[gtid * 2]     = lo;
    ((u32*)p.segbf)[gtid * 2 + 1] = hi;
  }
  // (c) G GEMM: 64x64 tile; waves (wm 2) x (wn 4).
  const int rh = b / 24, nc = b % 24;
  const int wv = tid >> 6, wm = wv >> 2, wn = wv & 3;
  const int lr = (tid >> 4) & 3, lc = tid & 15;
  __shared__ u16 sm[16384];           // A0|A1|B0|B1, 4KB-units (u16 idx 4096)
  const u16* Ab = p.ring + ((p.t - 1) & 7) * SLOT + rh * 64 * H;
  const u16* Wb = p.WT + 2 * TH * H;  // wld_WiT

  f32x4 acc[2];
  f32x4 zero = {0.f, 0.f, 0.f, 0.f};
  acc[0] = zero; acc[1] = zero;

  for (int kc = 0; kc < H; kc += 128) {
    __syncthreads();
#pragma unroll
    for (int it = 0; it < 4; ++it) {
      int u = it * 512 + tid;           // 0..2047
      int q = u >> 9;                   // 0:A0 1:A1 2:B0 3:B1
      int m = (u >> 3) & 63, g = u & 7;
      int gs = g ^ (m & 7);
      int ko = kc + ((q & 1) << 6) + gs * 8;
      const u16* src = (q < 2) ? (Ab + m * H + ko)
                               : (Wb + (nc * 64 + m) * H + ko);
      gload16(src, sm + (it * 512 + (tid & 448)) * 8);
    }
    __syncthreads();
#pragma unroll
    for (int c = 0; c < 2; ++c)
#pragma unroll
      for (int s2 = 0; s2 < 2; ++s2) {
        const int gk = s2 * 4 + lr;
        short8 bv = lds_frag(sm + (2 + c) * 4096, wn * 16 + lc, gk);
#pragma unroll
        for (int mt = 0; mt < 2; ++mt)
          acc[mt] = mfma16(
              lds_frag(sm + c * 4096, wm * 32 + mt * 16 + lc, gk), bv, acc[mt]);
      }
  }
  const int colb = nc * 64 + wn * 16 + lc;
  const float bi = p.wldbi[colb];
#pragma unroll
  for (int mt = 0; mt < 2; ++mt)
#pragma unroll
    for (int i = 0; i < 4; ++i)
      p.G[(rh * 64 + wm * 32 + mt * 16 + lr * 4 + i) * TH + colb] = acc[mt][i] + bi;
}

// ---------------------------------------------------------------------------
// k_big(t), 512 threads/block, grid 560:
//   blocks 0..495 : world GRU. 64x192 tile, 8 waves (2M x 4N), gload16.
//   blocks 496..559: sdc GRU. waves 0..3 active (4..7 exit), gload16 from
//   segbf/ring. No cross-block sync anywhere.
// ---------------------------------------------------------------------------
__global__ __launch_bounds__(512) void k_big(P p) {
  const int b = blockIdx.x, tid = threadIdx.x;
  const int lr = (tid >> 4) & 3, lc = tid & 15;
  __shared__ u16 sm[16384];           // 32 KB
  const int tp = (p.t - 1) & 7, tn = p.t & 7;
  const float* whfP = p.whf + ((p.t - 1) & 1) * SLOT;
  float* whfN = p.whf + (p.t & 1) * SLOT;
  u16* ringN = p.ring + tn * SLOT;

  if (b < 496) {  // ---- world GRU: 8 waves = 2 row-halves x 4 col-quarters ----
    const int wv = tid >> 6, wm = wv >> 2, wn = wv & 3;
    const int rt = b >> 3, cg = b & 7;
    const u16* Abase = p.ring + tp * SLOT + (S + rt * 64) * H;
    const u16* Bbase = p.WT + 3 * TH * H;      // wld_WhT
    f32x4 acc[3][2];
    f32x4 zero = {0.f, 0.f, 0.f, 0.f};
#pragma unroll
    for (int g = 0; g < 3; ++g) { acc[g][0] = zero; acc[g][1] = zero; }

    for (int kc = 0; kc < H; kc += 64) {
      __syncthreads();
#pragma unroll
      for (int it = 0; it < 4; ++it) {
        int u = it * 512 + tid;
        int gs = (u ^ (u >> 3)) & 7;
        const u16* src;
        if (u < 512) {
          src = Abase + (u >> 3) * H + kc + gs * 8;
        } else {
          int v = u - 512;
          int g = v >> 9, m = (v >> 3) & 63;
          src = Bbase + (g * H + cg * 64 + m) * H + kc + gs * 8;
        }
        gload16(src, sm + (it * 512 + (tid & 448)) * 8);
      }
      __syncthreads();
#pragma unroll
      for (int s2 = 0; s2 < 2; ++s2) {
        const int gk = s2 * 4 + lr;
        short8 av[2], bv[3];
#pragma unroll
        for (int mt = 0; mt < 2; ++mt)
          av[mt] = lds_frag(sm, wm * 32 + mt * 16 + lc, gk);
#pragma unroll
        for (int g = 0; g < 3; ++g)
          bv[g] = lds_frag(sm + 4096 + g * 4096, wn * 16 + lc, gk);
#pragma unroll
        for (int g = 0; g < 3; ++g)
#pragma unroll
          for (int mt = 0; mt < 2; ++mt) acc[g][mt] = mfma16(av[mt], bv[g], acc[g][mt]);
      }
    }
    const int col = cg * 64 + wn * 16 + lc;
    const float bhr = p.wldbh[col], bhz = p.wldbh[H + col], bhn = p.wldbh[2 * H + col];
    u32* sb = p.segb + (p.t & 1) * SEGSZ;
    int curSc = -1; float curMx = 0.f;
#pragma unroll
    for (int mt = 0; mt < 2; ++mt)
#pragma unroll
      for (int i = 0; i < 4; ++i) {
        int wrow = rt * 64 + wm * 32 + mt * 16 + lr * 4 + i;
        int grow = S + wrow;
        int scen = p.seg[wrow];
        const float* Gr = p.G + scen * TH;
        float r = sigm(Gr[col]          + acc[0][mt][i] + bhr);
        float z = sigm(Gr[H + col]      + acc[1][mt][i] + bhz);
        float n = tanh_(Gr[2 * H + col] + r * (acc[2][mt][i] + bhn));
        float h = whfP[grow * H + col];
        float h2 = (1.f - z) * n + z * h;
        whfN[grow * H + col] = h2;
        ringN[grow * H + col] = f2bf(h2);
        if (scen == curSc) curMx = fmaxf(curMx, h2);
        else {
          if (curSc >= 0) atomicMax(sb + curSc * H + col, flipf(curMx));
          curSc = scen; curMx = h2;
        }
      }
    atomicMax(sb + curSc * H + col, flipf(curMx));
  } else {        // ---- sdc GRU: waves 0..3 only ----
    const int w = tid >> 6;
    if (w >= 4) return;                 // exited waves don't join barriers
    const int ab = b - 496, rh = ab >> 5, cgx = ab & 31;
    f32x4 ai[3], ah[3];
    f32x4 zero = {0.f, 0.f, 0.f, 0.f};
#pragma unroll
    for (int g = 0; g < 3; ++g) { ai[g] = zero; ah[g] = zero; }

    for (int pass = 0; pass < 2; ++pass) {
      const u16* A  = pass ? (p.ring + tp * SLOT + rh * 64 * H)
                           : (p.segbf + rh * 64 * H);
      const u16* BT = p.WT + (pass ? 1 : 0) * TH * H;   // sdcWhT : sdcWiT
      for (int kc = 0; kc < H; kc += 64) {
        __syncthreads();
#pragma unroll
        for (int it = 0; it < 4; ++it) {
          int u = it * 256 + tid;
          if (u < 896) {
            int gs = (u ^ (u >> 3)) & 7;
            const u16* src;
            if (u < 512) {
              src = A + (u >> 3) * H + kc + gs * 8;
            } else {
              int v = u - 512;
              int m = v >> 3;            // 0..47
              src = BT + ((m >> 4) * H + cgx * 16 + (m & 15)) * H + kc + gs * 8;
            }
            gload16(src, sm + (it * 256 + (tid & 192)) * 8);
          }
        }
        __syncthreads();
#pragma unroll
        for (int s2 = 0; s2 < 2; ++s2) {
          const int gk = s2 * 4 + lr;
          short8 a = lds_frag(sm, w * 16 + lc, gk);
#pragma unroll
          for (int g = 0; g < 3; ++g) {
            f32x4 r = pass ? ah[g] : ai[g];
            r = mfma16(a, lds_frag(sm + 4096, g * 16 + lc, gk), r);
            if (pass) ah[g] = r; else ai[g] = r;
          }
        }
      }
    }
    const int col = cgx * 16 + lc;
    const float bir = p.sdcbi[col], biz = p.sdcbi[H + col], bin = p.sdcbi[2 * H + col];
    const float bhr = p.sdcbh[col], bhz = p.sdcbh[H + col], bhn = p.sdcbh[2 * H + col];
#pragma unroll
    for (int i = 0; i < 4; ++i) {
      int srow = rh * 64 + w * 16 + lr * 4 + i;
      float r = sigm(ai[0][i] + bir + ah[0][i] + bhr);
      float z = sigm(ai[1][i] + biz + ah[1][i] + bhz);
      float n = tanh_(ai[2][i] + bin + r * (ah[2][i] + bhn));
      float h = whfP[srow * H + col];
      float h2 = (1.f - z) * n + z * h;
      whfN[srow * H + col] = h2;
      ringN[srow * H + col] = f2bf(h2);
    }
  }
}

// ---------------------------------------------------------------------------
// k_mlp (R2 exact): layer1 GEMM (128x128 tiles) + fused leaky+layer2 partials.
// Grid 1024 = (8 slot x 32 rtile) x 4 ct.
// ---------------------------------------------------------------------------
__global__ __launch_bounds__(256) void k_mlp(P p) {
  const int b = blockIdx.x, tid = threadIdx.x;
  const int rt = b >> 2, ct = b & 3;
  const int slot = rt >> 5, rtile = rt & 31;
  const bool sdc = (rtile == 0);
  const int w = tid >> 6, lr = (tid >> 4) & 3, lc = tid & 15;
  __shared__ u16 sm[16384];
  const u16* A  = p.ring + slot * SLOT + rtile * 128 * H;
  const u16* Bb = p.o1T + (sdc ? 0 : 1) * H * H + (ct * 128) * H;
  const float* o1b = sdc ? p.sdco1b : p.wldo1b;
  const float* o2W = sdc ? p.sdco2W : p.wldo2W;

  f32x4 acc[8][2];
  f32x4 zero = {0.f, 0.f, 0.f, 0.f};
#pragma unroll
  for (int mt = 0; mt < 8; ++mt) { acc[mt][0] = zero; acc[mt][1] = zero; }

  for (int kc = 0; kc < H; kc += 64) {
    __syncthreads();
#pragma unroll
    for (int it = 0; it < 8; ++it) {
      int u = it * 256 + tid;
      int gs = (u ^ (u >> 3)) & 7;
      const u16* src;
      if (u < 1024) src = A  + (u >> 3) * H + kc + gs * 8;
      else          src = Bb + ((u >> 3) & 127) * H + kc + gs * 8;
      gload16(src, sm + (it * 256 + (tid & 192)) * 8);
    }
    __syncthreads();
#pragma unroll
    for (int s2 = 0; s2 < 2; ++s2) {
      const int gk = s2 * 4 + lr;
      short8 av[8], bv[2];
#pragma unroll
      for (int mt = 0; mt < 8; ++mt) av[mt] = lds_frag(sm, mt * 16 + lc, gk);
#pragma unroll
      for (int c2 = 0; c2 < 2; ++c2) bv[c2] = lds_frag(sm + 8192, w * 32 + c2 * 16 + lc, gk);
#pragma unroll
      for (int mt = 0; mt < 8; ++mt)
#pragma unroll
        for (int c2 = 0; c2 < 2; ++c2) acc[mt][c2] = mfma16(av[mt], bv[c2], acc[mt][c2]);
    }
  }
  __syncthreads();
  float* red = (float*)sm;
#pragma unroll
  for (int mt = 0; mt < 8; ++mt) {
    float q0[4] = {0.f, 0.f, 0.f, 0.f}, q1[4] = {0.f, 0.f, 0.f, 0.f};
#pragma unroll
    for (int c2 = 0; c2 < 2; ++c2) {
      int col = ct * 128 + w * 32 + c2 * 16 + lc;
      float b1 = o1b[col], w0 = o2W[col * 2], w1 = o2W[col * 2 + 1];
#pragma unroll
      for (int i = 0; i < 4; ++i) {
        float v = acc[mt][c2][i] + b1;
        v = v > 0.f ? v : 0.1f * v;
        q0[i] += v * w0; q1[i] += v * w1;
      }
    }
#pragma unroll
    for (int off = 1; off < 16; off <<= 1)
#pragma unroll
      for (int i = 0; i < 4; ++i) {
        q0[i] += __shfl_xor(q0[i], off);
        q1[i] += __shfl_xor(q1[i], off);
      }
    if (lc == 0)
#pragma unroll
      for (int i = 0; i < 4; ++i) {
        int row = mt * 16 + lr * 4 + i;
        red[(w * 128 + row) * 2 + 0] = q0[i];
        red[(w * 128 + row) * 2 + 1] = q1[i];
      }
  }
  __syncthreads();
  {
    int row = tid >> 1, od = tid & 1;
    float sum = red[(0 * 128 + row) * 2 + od] + red[(1 * 128 + row) * 2 + od] +
                red[(2 * 128 + row) * 2 + od] + red[(3 * 128 + row) * 2 + od];
    int r = slot * 4096 + rtile * 128 + row;
    p.part[ct * 65536 + r * 2 + od] = sum;
  }
}

// k_mlp2: out = sum of 4 col-quarter partials + o2 bias. Grid 64.
__global__ __launch_bounds__(256) void k_mlp2(P p) {
  const int gtid = blockIdx.x * 256 + threadIdx.x;
  for (int i = gtid; i < 65536; i += 16384) {
    int r = i >> 1, od = i & 1;
    int row = r & 4095, slot = r >> 12;
    float v = p.part[i] + p.part[65536 + i] + p.part[131072 + i] + p.part[196608 + i];
    v += (row < S ? p.sdco2b : p.wldo2b)[od];
    p.out[row * 160 + (p.t + slot) * 2 + od] = v;
  }
}

// ---------------------------------------------------------------------------
extern "C" void kernel_launch(void* const* d_in, const int* in_sizes, int n_in,
                              void* d_out, int out_size, void* d_ws, size_t ws_size,
                              hipStream_t stream) {
  P prm;
  prm.goals  = (const float*)d_in[0];
  prm.dyn    = (const float*)d_in[1];
  prm.ccls   = (const float*)d_in[2];
  prm.inte   = (const float*)d_in[3];
  prm.seg    = (const int*)  d_in[4];
  prm.sdc_h0 = (const float*)d_in[5];
  prm.wld_h0 = (const float*)d_in[6];
  prm.golW   = (const float*)d_in[7];
  prm.golb   = (const float*)d_in[8];
  prm.sdcWi  = (const float*)d_in[9];
  prm.sdcWh  = (const float*)d_in[10];
  prm.sdcbi  = (const float*)d_in[11];
  prm.sdcbh  = (const float*)d_in[12];
  prm.wldWi  = (const float*)d_in[13];
  prm.wldWh  = (const float*)d_in[14];
  prm.wldbi  = (const float*)d_in[15];
  prm.wldbh  = (const float*)d_in[16];
  prm.sdco1W = (const float*)d_in[17];
  prm.sdco1b = (const float*)d_in[18];
  prm.sdco2W = (const float*)d_in[19];
  prm.sdco2b = (const float*)d_in[20];
  prm.wldo1W = (const float*)d_in[21];
  prm.wldo1b = (const float*)d_in[22];
  prm.wldo2W = (const float*)d_in[23];
  prm.wldo2b = (const float*)d_in[24];
  prm.out = (float*)d_out;

  char* ws = (char*)d_ws;
  prm.whf   = (float*)(ws + 0);              // 16,777,216 B
  prm.ring  = (u16*)  (ws + 16777216);       // 33,554,432 B
  prm.enc   = (u16*)  (ws + 50331648);       //  4,194,304 B
  prm.WT    = (u16*)  (ws + 54525952);       //  6,291,456 B
  prm.o1T   = (u16*)  (ws + 60817408);       //  1,048,576 B
  prm.G     = (float*)(ws + 61865984);       //    786,432 B
  prm.segb  = (u32*)  (ws + 62652416);       //    524,288 B (x2 buffers)
  prm.segbf = (u16*)  (ws + 50331648);           // aliases enc (dead after t=0)
  prm.part  = (float*)(ws + 50331648 + 131072);  // aliases enc+128KB (1 MB)

  prm.t = 0;
  k_prep<<<1028, 256, 0, stream>>>(prm);
  k_big0<<<512, 256, 0, stream>>>(prm);
  for (int t = 1; t < 80; ++t) {
    prm.t = t;
    k_small<<<48, 512, 0, stream>>>(prm);
    k_big<<<560, 512, 0, stream>>>(prm);
    if ((t & 7) == 7) {
      P pm = prm;
      pm.t = t - 7;
      k_mlp<<<1024, 256, 0, stream>>>(pm);
      k_mlp2<<<64, 256, 0, stream>>>(pm);
    }
  }
}